// Round 8
// baseline (400.369 us; speedup 1.0000x reference)
//
#include <hip/hip_runtime.h>
#include <stdint.h>

#define NTOK   131072
#define DM     1024
#define NE     64
#define TB     128        // tokens per gate block
#define NBLK   1024       // NTOK / TB
#define BK     32         // K chunk
#define NCHUNK 32         // DM / BK
#define CAP    2458       // ceil(1.2 * 131072 / 64)
#define TAU    0.005f     // rescue threshold: >> ~1e-5 accumulation noise

typedef __attribute__((ext_vector_type(8))) short bf16x8;
typedef __attribute__((ext_vector_type(4))) float f32x4;

union Frag { bf16x8 v; unsigned short u[8]; uint4 q; };

// RNE fp32 -> bf16 bits (finite inputs; residual subtractions exact)
__device__ __forceinline__ unsigned short f2bf_rne(float x) {
    uint32_t u = __float_as_uint(x);
    u += 0x7FFFu + ((u >> 16) & 1u);
    return (unsigned short)(u >> 16);
}
__device__ __forceinline__ float bf2f(unsigned short h) {
    return __uint_as_float(((uint32_t)h) << 16);
}

// global -> LDS direct. NOTE (R7 bug): gptr must be the PER-LANE address;
// HW writes each lane's 16B to uniform lds base + lane*16.
__device__ __forceinline__ void gload_lds16(const float* g, float* l) {
    __builtin_amdgcn_global_load_lds(
        (const __attribute__((address_space(1))) void*)g,
        (__attribute__((address_space(3))) void*)l, 16, 0, 0);
}

// ---------------------------------------------------------------------------
// wprep: split W (1024x64 fp32) into 3 bf16 planes in MFMA B-frag order.
// Wp[(c*12 + t*3 + p)*64 + l] = 16B frag: col = t*16+(l&15), k = c*32+(l>>4)*8+j.
// ---------------------------------------------------------------------------
__global__ __launch_bounds__(256)
void wprep_kernel(const float* __restrict__ W, uint4* __restrict__ Wp)
{
    const int c = blockIdx.x;          // k-chunk 0..31
    const int t = threadIdx.x >> 6;    // n-tile 0..3
    const int l = threadIdx.x & 63;
    Frag p1, p2, p3;
#pragma unroll
    for (int j = 0; j < 8; ++j) {
        const float wv = W[(size_t)(c * 32 + (l >> 4) * 8 + j) * NE + t * 16 + (l & 15)];
        const unsigned short h1 = f2bf_rne(wv);
        const float r1 = wv - bf2f(h1);
        const unsigned short h2 = f2bf_rne(r1);
        const unsigned short h3 = f2bf_rne(r1 - bf2f(h2));
        p1.u[j] = h1; p2.u[j] = h2; p3.u[j] = h3;
    }
    uint4* base = Wp + (size_t)(c * 12 + t * 3) * 64;
    base[0 * 64 + l] = p1.q;
    base[1 * 64 + l] = p2.q;
    base[2 * 64 + l] = p3.q;
}

// ---------------------------------------------------------------------------
// gate_kernel (MFMA): 4 waves x 32 tokens, all 64 experts. Exact 3-way bf16
// split: a·w = a1w1+a1w2+a2w1+a1w3+a2w2+a3w1 (err ~1e-5 relative to fp32 ref,
// borderline tokens handled by rescue_kernel). Emits choice/top1/gap/colsums.
// R7 FIX: W staging source is per-lane (Wp + idx*64 + lane), was uniform.
// ---------------------------------------------------------------------------
__global__ __launch_bounds__(256, 2)
void gate_kernel(const float* __restrict__ A, const uint4* __restrict__ Wp,
                 const float* __restrict__ bias, const float* __restrict__ noise,
                 float* __restrict__ out, int* __restrict__ bi_arr,
                 float* __restrict__ gapf, float* __restrict__ colpart)
{
    __shared__ __align__(16) float asA[2][TB][BK];   // 32 KB, linear + XOR swizzle
    __shared__ uint4 bFr[2][12][64];                 // 24 KB, frag-ordered
    __shared__ float wcol[4][NE];

    const int tid  = threadIdx.x;
    const int lane = tid & 63;
    const int w    = __builtin_amdgcn_readfirstlane(tid >> 6);
    const int blk  = blockIdx.x;
    const int tokBase = blk * TB;
    const int g    = lane >> 4;
    const int e16  = lane & 15;

    f32x4 acc[2][4];
#pragma unroll
    for (int mt = 0; mt < 2; ++mt)
#pragma unroll
        for (int nt = 0; nt < 4; ++nt)
            acc[mt][nt] = (f32x4){0.f, 0.f, 0.f, 0.f};

    const int sl = (lane & 7) ^ ((lane >> 3) & 7);
    const float* aBase = A + (size_t)(tokBase + w * 32 + (lane >> 3)) * DM + sl * 4;

    // prologue: stage chunk 0 (7 outstanding/wave: 4 A + 3 W)
#pragma unroll
    for (int q = 0; q < 4; ++q)
        gload_lds16(aBase + (size_t)q * 8 * DM, &asA[0][w * 32 + q * 8][0]);
#pragma unroll
    for (int v = 0; v < 3; ++v) {
        const int u = w + 4 * v;
        gload_lds16((const float*)(Wp + (size_t)u * 64 + lane), (float*)&bFr[0][u][0]);
    }

#pragma unroll 1
    for (int c = 0; c < NCHUNK; ++c) {
        const int cur = c & 1;
        __builtin_amdgcn_s_barrier();            // B1: WAR fence (no drain)
        asm volatile("" ::: "memory");
        if (c + 1 < NCHUNK) {
            const int cn = c + 1;
#pragma unroll
            for (int q = 0; q < 4; ++q)
                gload_lds16(aBase + (size_t)q * 8 * DM + cn * BK,
                            &asA[cur ^ 1][w * 32 + q * 8][0]);
#pragma unroll
            for (int v = 0; v < 3; ++v) {
                const int u = w + 4 * v;
                gload_lds16((const float*)(Wp + ((size_t)cn * 12 + u) * 64 + lane),
                            (float*)&bFr[cur ^ 1][u][0]);
            }
            asm volatile("s_waitcnt vmcnt(7)" ::: "memory");  // chunk c landed
        } else {
            asm volatile("s_waitcnt vmcnt(0)" ::: "memory");
        }
        __builtin_amdgcn_sched_barrier(0);
        __builtin_amdgcn_s_barrier();            // B2: chunk c visible
        asm volatile("" ::: "memory");

        Frag bf[4][3];
#pragma unroll
        for (int nt = 0; nt < 4; ++nt)
#pragma unroll
            for (int p = 0; p < 3; ++p)
                bf[nt][p].q = bFr[cur][nt * 3 + p][lane];

        Frag a1[2], a2[2], a3[2];
#pragma unroll
        for (int mt = 0; mt < 2; ++mt) {
            const int row = w * 32 + mt * 16 + e16;   // row&7 == lane&7
            const float* rp = &asA[cur][row][0];
            const float4 x0 = *(const float4*)(rp + (((2 * g)     ^ (lane & 7)) << 2));
            const float4 x1 = *(const float4*)(rp + (((2 * g + 1) ^ (lane & 7)) << 2));
            const float xs[8] = {x0.x, x0.y, x0.z, x0.w, x1.x, x1.y, x1.z, x1.w};
#pragma unroll
            for (int j = 0; j < 8; ++j) {
                const float x = xs[j];
                const unsigned short h1 = f2bf_rne(x);
                const float r1 = x - bf2f(h1);
                const unsigned short h2 = f2bf_rne(r1);
                const unsigned short h3 = f2bf_rne(r1 - bf2f(h2));
                a1[mt].u[j] = h1; a2[mt].u[j] = h2; a3[mt].u[j] = h3;
            }
        }

#pragma unroll
        for (int mt = 0; mt < 2; ++mt)
#pragma unroll
            for (int nt = 0; nt < 4; ++nt) {
                f32x4 d = acc[mt][nt];
                d = __builtin_amdgcn_mfma_f32_16x16x32_bf16(a1[mt].v, bf[nt][0].v, d, 0, 0, 0);
                d = __builtin_amdgcn_mfma_f32_16x16x32_bf16(a1[mt].v, bf[nt][1].v, d, 0, 0, 0);
                d = __builtin_amdgcn_mfma_f32_16x16x32_bf16(a2[mt].v, bf[nt][0].v, d, 0, 0, 0);
                d = __builtin_amdgcn_mfma_f32_16x16x32_bf16(a1[mt].v, bf[nt][2].v, d, 0, 0, 0);
                d = __builtin_amdgcn_mfma_f32_16x16x32_bf16(a2[mt].v, bf[nt][1].v, d, 0, 0, 0);
                d = __builtin_amdgcn_mfma_f32_16x16x32_bf16(a3[mt].v, bf[nt][0].v, d, 0, 0, 0);
                acc[mt][nt] = d;
            }
    }

    // ---- epilogue: bias+noise, per-token argmax/gap/softmax ----
#pragma unroll
    for (int mt = 0; mt < 2; ++mt)
#pragma unroll
        for (int r = 0; r < 4; ++r) {
            const int T = tokBase + w * 32 + mt * 16 + g * 4 + r;
#pragma unroll
            for (int nt = 0; nt < 4; ++nt) {
                const float nz = noise[(size_t)T * NE + nt * 16 + e16];
                acc[mt][nt][r] += bias[nt * 16 + e16] + nz * 0.2f + 0.9f;
            }
        }

    float cw[4] = {0.f, 0.f, 0.f, 0.f};
#pragma unroll
    for (int mt = 0; mt < 2; ++mt)
#pragma unroll
        for (int r = 0; r < 4; ++r) {
            const int T = tokBase + w * 32 + mt * 16 + g * 4 + r;
            float raw[4];
#pragma unroll
            for (int nt = 0; nt < 4; ++nt) raw[nt] = acc[mt][nt][r];

            float v = raw[0]; int be = e16;
#pragma unroll
            for (int nt = 1; nt < 4; ++nt)
                if (raw[nt] > v) { v = raw[nt]; be = nt * 16 + e16; }
#pragma unroll
            for (int m = 1; m <= 8; m <<= 1) {
                const float vo = __shfl_xor(v, m, 64);
                const int   eo = __shfl_xor(be, m, 64);
                if (vo > v || (vo == v && eo < be)) { v = vo; be = eo; }
            }
            float m2 = -1e30f;                          // runner-up (for gap)
#pragma unroll
            for (int nt = 0; nt < 4; ++nt)
                if (nt * 16 + e16 != be && raw[nt] > m2) m2 = raw[nt];
#pragma unroll
            for (int m = 1; m <= 8; m <<= 1)
                m2 = fmaxf(m2, __shfl_xor(m2, m, 64));

            float d = 0.f, pr[4];
#pragma unroll
            for (int nt = 0; nt < 4; ++nt) { pr[nt] = __expf(raw[nt] - v); d += pr[nt]; }
#pragma unroll
            for (int m = 1; m <= 8; m <<= 1) d += __shfl_xor(d, m, 64);
            const float inv = 1.0f / d;
#pragma unroll
            for (int nt = 0; nt < 4; ++nt) cw[nt] += pr[nt] * inv;

            if (e16 == mt * 4 + r) {                    // one writer per (g,mt,r)
                out[NTOK + T] = inv;
                bi_arr[T]     = be;
                gapf[T]       = v - m2;
            }
        }

#pragma unroll
    for (int nt = 0; nt < 4; ++nt) {
        cw[nt] += __shfl_xor(cw[nt], 16, 64);
        cw[nt] += __shfl_xor(cw[nt], 32, 64);
    }
    if (lane < 16) {
#pragma unroll
        for (int nt = 0; nt < 4; ++nt) wcol[w][nt * 16 + lane] = cw[nt];
    }
    __syncthreads();
    if (tid < NE)
        colpart[blk * NE + tid] = wcol[0][tid] + wcol[1][tid] + wcol[2][tid] + wcol[3][tid];
}

// ---------------------------------------------------------------------------
// rescue_kernel: tokens with top-2 gap < TAU recomputed with the bit-identical
// R5 sequential-fmaf chain (k ascending, same bias/noise expression) so
// borderline argmax decisions reproduce the proven-passing fp32 path.
// ---------------------------------------------------------------------------
__global__ __launch_bounds__(64)
void rescue_kernel(const float* __restrict__ A, const float* __restrict__ W,
                   const float* __restrict__ bias, const float* __restrict__ noise,
                   const float* __restrict__ gapf, int* __restrict__ bi_arr,
                   float* __restrict__ out)
{
    const int b    = blockIdx.x;        // 128-token block
    const int lane = threadIdx.x;       // expert id
#pragma unroll 1
    for (int h = 0; h < 2; ++h) {
        const int t0 = b * 128 + h * 64;
        uint64_t mask = __ballot(gapf[t0 + lane] < TAU);
        while (mask) {
            const int s = __builtin_ctzll(mask); mask &= mask - 1;
            const int t = t0 + s;
            const float* arow = A + (size_t)t * DM;
            float acc = 0.f;
#pragma unroll 8
            for (int k = 0; k < DM; ++k)
                acc = fmaf(arow[k], W[(size_t)k * NE + lane], acc);
            acc += bias[lane] + noise[(size_t)t * NE + lane] * 0.2f + 0.9f;

            float v = acc; int be = lane;
#pragma unroll
            for (int m = 1; m <= 32; m <<= 1) {
                const float vo = __shfl_xor(v, m, 64);
                const int   eo = __shfl_xor(be, m, 64);
                if (vo > v || (vo == v && eo < be)) { v = vo; be = eo; }
            }
            float d = __expf(acc - v);
#pragma unroll
            for (int m = 1; m <= 32; m <<= 1) d += __shfl_xor(d, m, 64);
            if (lane == 0) { bi_arr[t] = be; out[NTOK + t] = 1.0f / d; }
        }
    }
}

// ---------------------------------------------------------------------------
// rank_kernel: stable within-128-block rank + histogram via ballots.
// ---------------------------------------------------------------------------
__global__ __launch_bounds__(64)
void rank_kernel(const int* __restrict__ bi_arr, int* __restrict__ pk,
                 int* __restrict__ histg)
{
    const int b    = blockIdx.x;
    const int lane = threadIdx.x;
    const uint64_t below = (1ull << lane) - 1ull;
    const int t0 = b * 128;
    const int b0 = bi_arr[t0 + lane];
    const int b1 = bi_arr[t0 + 64 + lane];
    int lr0 = 0, lr1 = 0, h0 = 0, h1 = 0, h0my = 0;
#pragma unroll 1
    for (int e = 0; e < NE; ++e) {
        const uint64_t m0 = __ballot(b0 == e);
        const uint64_t m1 = __ballot(b1 == e);
        if (b0 == e)   lr0 = (int)__popcll(m0 & below);
        if (b1 == e) { lr1 = (int)__popcll(m1 & below); h0my = (int)__popcll(m0); }
        if (lane == e) { h0 = (int)__popcll(m0); h1 = (int)__popcll(m1); }
    }
    pk[t0 + lane]      = b0 | (lr0 << 6);
    pk[t0 + 64 + lane] = b1 | ((lr1 + h0my) << 6);
    histg[b * NE + lane] = h0 + h1;
}

// ---------------------------------------------------------------------------
// scan / loss / finalize (logic unchanged, proven in R5)
// ---------------------------------------------------------------------------
__global__ __launch_bounds__(256)
void scan_kernel(int* __restrict__ hist, const float* __restrict__ colpart,
                 int* __restrict__ totals, float* __restrict__ colsums)
{
    __shared__ int   wtot[4];
    __shared__ float wcs[4];
    const int e = blockIdx.x, t = threadIdx.x, lane = t & 63, w = t >> 6;

    int h[4]; int s = 0; float csl = 0.f;
#pragma unroll
    for (int i = 0; i < 4; ++i) {
        h[i] = hist[(t * 4 + i) * NE + e];
        csl += colpart[(t * 4 + i) * NE + e];
        s   += h[i];
    }
    int inc = s;
#pragma unroll
    for (int d = 1; d < 64; d <<= 1) {
        const int v = __shfl_up(inc, d, 64);
        if (lane >= d) inc += v;
    }
    float wsum = csl;
#pragma unroll
    for (int m = 32; m; m >>= 1) wsum += __shfl_xor(wsum, m, 64);
    if (lane == 63) wtot[w] = inc;
    if (lane == 0)  wcs[w]  = wsum;
    __syncthreads();

    int base = 0;
#pragma unroll
    for (int ww = 0; ww < 4; ++ww) base += (ww < w) ? wtot[ww] : 0;
    int run = base + inc - s;
#pragma unroll
    for (int i = 0; i < 4; ++i) { hist[(t * 4 + i) * NE + e] = run; run += h[i]; }

    if (t == 0) {
        totals[e]  = wtot[0] + wtot[1] + wtot[2] + wtot[3];
        colsums[e] = wcs[0] + wcs[1] + wcs[2] + wcs[3];
    }
}

__global__ void loss_kernel(const int* __restrict__ totals,
                            const float* __restrict__ colsums,
                            float* __restrict__ out)
{
    const int e   = threadIdx.x;
    const int tot = totals[e];
    const float cnt = (float)((tot < CAP) ? tot : CAP);
    float nv = cnt, contrib = cnt * colsums[e];
#pragma unroll
    for (int m = 32; m; m >>= 1) {
        nv      += __shfl_xor(nv, m, 64);
        contrib += __shfl_xor(contrib, m, 64);
    }
    if (e == 0) out[2 * NTOK] = 64.0f * contrib / (nv * nv);
}

__global__ void finalize_kernel(const int* __restrict__ pk, const int* __restrict__ offs,
                                float* __restrict__ out)
{
    const int i = blockIdx.x * 256 + threadIdx.x;
    const int v = pk[i];
    const int e = v & 63;
    const int r = (v >> 6) + offs[(i >> 7) * NE + e];
    out[i] = (r < CAP) ? (float)e : -1.0f;
}

extern "C" void kernel_launch(void* const* d_in, const int* in_sizes, int n_in,
                              void* d_out, int out_size, void* d_ws, size_t ws_size,
                              hipStream_t stream)
{
    (void)in_sizes; (void)n_in; (void)out_size; (void)ws_size;
    const float* A     = (const float*)d_in[0];
    const float* W     = (const float*)d_in[1];
    const float* bias  = (const float*)d_in[2];
    const float* noise = (const float*)d_in[3];
    float* out = (float*)d_out;

    char* ws = (char*)d_ws;
    int*   bi_arr  = (int*)ws;                         // 512 KB
    float* gapf    = (float*)(ws + 524288);            // 512 KB (gate->rescue)
    int*   pk      = (int*)(ws + 524288);              // aliased: rank(after rescue)->finalize
    int*   histg   = (int*)(ws + 1048576);             // 256 KB
    float* colpart = (float*)(ws + 1310720);           // 256 KB
    int*   totals  = (int*)(ws + 1572864);             // 256 B
    float* colsums = (float*)(ws + 1573120);           // 256 B
    uint4* Wp      = (uint4*)(ws + 1576960);           // 384 KB

    wprep_kernel<<<NCHUNK, 256, 0, stream>>>(W, Wp);
    gate_kernel<<<NBLK, 256, 0, stream>>>(A, Wp, bias, noise, out, bi_arr, gapf, colpart);
    rescue_kernel<<<NBLK, 64, 0, stream>>>(A, W, bias, noise, gapf, bi_arr, out);
    rank_kernel<<<NBLK, 64, 0, stream>>>(bi_arr, pk, histg);
    scan_kernel<<<NE, 256, 0, stream>>>(histg, colpart, totals, colsums);
    loss_kernel<<<1, 64, 0, stream>>>(totals, colsums, out);
    finalize_kernel<<<NTOK / 256, 256, 0, stream>>>(pk, histg, out);
}

// Round 9
// 323.748 us; speedup vs baseline: 1.2367x; 1.2367x over previous
//
#include <hip/hip_runtime.h>
#include <stdint.h>

#define NTOK   131072
#define DM     1024
#define NE     64
#define TB     128        // tokens per gate block
#define NBLK   1024       // NTOK / TB
#define BK     32         // K chunk
#define NCHUNK 32         // DM / BK
#define CAP    2458       // ceil(1.2 * 131072 / 64)
#define TAU    0.005f     // rescue threshold: >> ~1e-5 split error

typedef __attribute__((ext_vector_type(8))) short bf16x8;
typedef __attribute__((ext_vector_type(4))) float f32x4;

union Frag { bf16x8 v; uint32_t w[4]; uint4 q; unsigned short u[8]; };

// RNE fp32 -> bf16 bits (wprep only)
__device__ __forceinline__ unsigned short f2bf_rne(float x) {
    uint32_t u = __float_as_uint(x);
    u += 0x7FFFu + ((u >> 16) & 1u);
    return (unsigned short)(u >> 16);
}
__device__ __forceinline__ float bf2f(unsigned short h) {
    return __uint_as_float(((uint32_t)h) << 16);
}

// ---------------------------------------------------------------------------
// wprep: split W (1024x64 fp32) into 2 bf16 planes in MFMA B-frag order.
// Wp[(c*8 + t*2 + p)*64 + l]: col = t*16+(l&15), k = c*32+(l>>4)*8+j.
// Also zeroes the rescue counter (runs before gate on the stream).
// ---------------------------------------------------------------------------
__global__ __launch_bounds__(256)
void wprep_kernel(const float* __restrict__ W, uint4* __restrict__ Wp, int* __restrict__ cnt)
{
    if (blockIdx.x == 0 && threadIdx.x == 0) *cnt = 0;
    const int c = blockIdx.x;          // k-chunk 0..31
    const int t = threadIdx.x >> 6;    // n-tile 0..3
    const int l = threadIdx.x & 63;
    Frag p1, p2;
#pragma unroll
    for (int j = 0; j < 8; ++j) {
        const float wv = W[(size_t)(c * 32 + (l >> 4) * 8 + j) * NE + t * 16 + (l & 15)];
        const unsigned short h1 = f2bf_rne(wv);
        const unsigned short h2 = f2bf_rne(wv - bf2f(h1));
        p1.u[j] = h1; p2.u[j] = h2;
    }
    uint4* base = Wp + (size_t)(c * 8 + t * 2) * 64;
    base[0 * 64 + l] = p1.q;
    base[1 * 64 + l] = p2.q;
}

// 2-plane split of 8 fp32 via packed HW convert (rounding-mode agnostic:
// the residual subtraction is exact for any rounding of the first plane).
struct ASet { float4 p00, p01, p10, p11; };
struct BSet { uint4 b[8]; };

__device__ __forceinline__ void splitA(const float4& P0, const float4& P1,
                                       Frag& A1, Frag& A2)
{
    const float xs[8] = {P0.x, P0.y, P0.z, P0.w, P1.x, P1.y, P1.z, P1.w};
#pragma unroll
    for (int j = 0; j < 4; ++j) {
        uint32_t p1, p2;
        asm("v_cvt_pk_bf16_f32 %0, %1, %2" : "=v"(p1) : "v"(xs[2*j]), "v"(xs[2*j+1]));
        const float f0 = __uint_as_float(p1 << 16);
        const float f1 = __uint_as_float(p1 & 0xffff0000u);
        const float r0 = xs[2*j] - f0;
        const float r1 = xs[2*j+1] - f1;
        asm("v_cvt_pk_bf16_f32 %0, %1, %2" : "=v"(p2) : "v"(r0), "v"(r1));
        A1.w[j] = p1; A2.w[j] = p2;
    }
}

// ---------------------------------------------------------------------------
// gate_kernel (R9): NO LDS in the K-loop, NO barriers. 4 waves x 32 tokens.
// Rationale (R8 post-mortem): A rows have zero cross-lane reuse here (each
// wave computes all 64 experts in-register), so LDS staging + barrier/vmcnt
// choreography was pure overhead and convoyed the block. Per-lane A fragment
// = 32 contiguous bytes -> two float4 global loads; full cache-line use.
// B frags stream from frag-ordered Wp (L2-resident). Depth-2 software
// pipeline over 3 named register sets (static indexing, rule #20).
// 3-term split MFMA: a·w ~= a1w1 + a1w2 + a2w1 (err ~5e-6 << TAU/2).
// ---------------------------------------------------------------------------
__global__ __launch_bounds__(256, 2)
void gate_kernel(const float* __restrict__ A, const uint4* __restrict__ Wp,
                 const float* __restrict__ bias, const float* __restrict__ noise,
                 float* __restrict__ out, int* __restrict__ bi_arr,
                 int* __restrict__ list, int* __restrict__ cnt,
                 float* __restrict__ colpart)
{
    __shared__ float wcol[4][NE];

    const int tid  = threadIdx.x;
    const int lane = tid & 63;
    const int w    = __builtin_amdgcn_readfirstlane(tid >> 6);
    const int blk  = blockIdx.x;
    const int tokBase = blk * TB;
    const int g    = lane >> 4;
    const int e16  = lane & 15;

    f32x4 acc[2][4];
#pragma unroll
    for (int mt = 0; mt < 2; ++mt)
#pragma unroll
        for (int nt = 0; nt < 4; ++nt)
            acc[mt][nt] = (f32x4){0.f, 0.f, 0.f, 0.f};

    // A rows owned by this lane: mt=0 -> row w*32+e16, mt=1 -> +16
    const float* aRow0 = A + (size_t)(tokBase + w * 32 + e16) * DM + g * 8;
    const float* aRow1 = aRow0 + (size_t)16 * DM;
    const uint4* wpb   = Wp + lane;

#define LOADA(c, S)  { S.p00 = *(const float4*)(aRow0 + (c) * BK);       \
                       S.p01 = *(const float4*)(aRow0 + (c) * BK + 4);   \
                       S.p10 = *(const float4*)(aRow1 + (c) * BK);       \
                       S.p11 = *(const float4*)(aRow1 + (c) * BK + 4); }
#define LOADB(c, S)  { const uint4* p_ = wpb + (size_t)(c) * 512;        \
                       _Pragma("unroll")                                 \
                       for (int f_ = 0; f_ < 8; ++f_) S.b[f_] = p_[f_ * 64]; }
#define COMPUTE(AS, BS) {                                                \
        Frag a1_[2], a2_[2];                                             \
        splitA(AS.p00, AS.p01, a1_[0], a2_[0]);                          \
        splitA(AS.p10, AS.p11, a1_[1], a2_[1]);                          \
        _Pragma("unroll")                                                \
        for (int mt_ = 0; mt_ < 2; ++mt_) {                              \
            _Pragma("unroll")                                            \
            for (int nt_ = 0; nt_ < 4; ++nt_) {                          \
                Frag b1_, b2_;                                           \
                b1_.q = BS.b[nt_ * 2];                                   \
                b2_.q = BS.b[nt_ * 2 + 1];                               \
                f32x4 d_ = acc[mt_][nt_];                                \
                d_ = __builtin_amdgcn_mfma_f32_16x16x32_bf16(a1_[mt_].v, b1_.v, d_, 0, 0, 0); \
                d_ = __builtin_amdgcn_mfma_f32_16x16x32_bf16(a1_[mt_].v, b2_.v, d_, 0, 0, 0); \
                d_ = __builtin_amdgcn_mfma_f32_16x16x32_bf16(a2_[mt_].v, b1_.v, d_, 0, 0, 0); \
                acc[mt_][nt_] = d_;                                      \
            }                                                            \
        }                                                                \
    }

    ASet As0, As1, As2; BSet Bs0, Bs1, Bs2;
    LOADA(0, As0) LOADB(0, Bs0)
    LOADA(1, As1) LOADB(1, Bs1)
#pragma unroll 1
    for (int c = 0; c < 30; c += 3) {
        LOADA(c + 2, As2) LOADB(c + 2, Bs2)
        COMPUTE(As0, Bs0)
        LOADA(c + 3, As0) LOADB(c + 3, Bs0)
        COMPUTE(As1, Bs1)
        LOADA(c + 4, As1) LOADB(c + 4, Bs1)
        COMPUTE(As2, Bs2)
    }
    COMPUTE(As0, Bs0)   // chunk 30
    COMPUTE(As1, Bs1)   // chunk 31
#undef LOADA
#undef LOADB
#undef COMPUTE

    // ---- epilogue: bias+noise, per-token argmax/softmax, rescue-list ----
    // C/D: token = w*32 + mt*16 + g*4 + r, expert = nt*16 + e16 (m89 layout)
#pragma unroll
    for (int mt = 0; mt < 2; ++mt)
#pragma unroll
        for (int r = 0; r < 4; ++r) {
            const int T = tokBase + w * 32 + mt * 16 + g * 4 + r;
#pragma unroll
            for (int nt = 0; nt < 4; ++nt) {
                const float nz = noise[(size_t)T * NE + nt * 16 + e16];
                acc[mt][nt][r] += bias[nt * 16 + e16] + nz * 0.2f + 0.9f;
            }
        }

    float cw[4] = {0.f, 0.f, 0.f, 0.f};
#pragma unroll
    for (int mt = 0; mt < 2; ++mt)
#pragma unroll
        for (int r = 0; r < 4; ++r) {
            const int T = tokBase + w * 32 + mt * 16 + g * 4 + r;
            float raw[4];
#pragma unroll
            for (int nt = 0; nt < 4; ++nt) raw[nt] = acc[mt][nt][r];

            float v = raw[0]; int be = e16;
#pragma unroll
            for (int nt = 1; nt < 4; ++nt)
                if (raw[nt] > v) { v = raw[nt]; be = nt * 16 + e16; }
#pragma unroll
            for (int m = 1; m <= 8; m <<= 1) {
                const float vo = __shfl_xor(v, m, 64);
                const int   eo = __shfl_xor(be, m, 64);
                if (vo > v || (vo == v && eo < be)) { v = vo; be = eo; }
            }
            float m2 = -1e30f;                          // runner-up
#pragma unroll
            for (int nt = 0; nt < 4; ++nt)
                if (nt * 16 + e16 != be && raw[nt] > m2) m2 = raw[nt];
#pragma unroll
            for (int m = 1; m <= 8; m <<= 1)
                m2 = fmaxf(m2, __shfl_xor(m2, m, 64));

            float d = 0.f, pr[4];
#pragma unroll
            for (int nt = 0; nt < 4; ++nt) { pr[nt] = __expf(raw[nt] - v); d += pr[nt]; }
#pragma unroll
            for (int m = 1; m <= 8; m <<= 1) d += __shfl_xor(d, m, 64);
            const float inv = 1.0f / d;
#pragma unroll
            for (int nt = 0; nt < 4; ++nt) cw[nt] += pr[nt] * inv;

            if (e16 == mt * 4 + r) {                    // one writer per (g,mt,r)
                out[NTOK + T] = inv;
                bi_arr[T]     = be;
                if (v - m2 < TAU) {                     // borderline -> rescue list
                    const int s = atomicAdd(cnt, 1);
                    list[s] = T;
                }
            }
        }

#pragma unroll
    for (int nt = 0; nt < 4; ++nt) {
        cw[nt] += __shfl_xor(cw[nt], 16, 64);
        cw[nt] += __shfl_xor(cw[nt], 32, 64);
    }
    if (lane < 16) {
#pragma unroll
        for (int nt = 0; nt < 4; ++nt) wcol[w][nt * 16 + lane] = cw[nt];
    }
    __syncthreads();
    if (tid < NE)
        colpart[blk * NE + tid] = wcol[0][tid] + wcol[1][tid] + wcol[2][tid] + wcol[3][tid];
}

// ---------------------------------------------------------------------------
// rescue: recompute listed tokens with the bit-identical R5 sequential-fmaf
// chain (k ascending). 4 tokens per wave-batch = 4 independent ILP chains,
// each chain preserving the exact proven summation order.
// ---------------------------------------------------------------------------
__device__ __forceinline__ void rescue_finish(int t, float sc, int lane,
                                              int* bi_arr, float* out)
{
    float v = sc; int be = lane;
#pragma unroll
    for (int m = 1; m <= 32; m <<= 1) {
        const float vo = __shfl_xor(v, m, 64);
        const int   eo = __shfl_xor(be, m, 64);
        if (vo > v || (vo == v && eo < be)) { v = vo; be = eo; }
    }
    float d = __expf(sc - v);
#pragma unroll
    for (int m = 1; m <= 32; m <<= 1) d += __shfl_xor(d, m, 64);
    if (lane == 0) { bi_arr[t] = be; out[NTOK + t] = 1.0f / d; }
}

__global__ __launch_bounds__(64)
void rescue_kernel(const float* __restrict__ A, const float* __restrict__ W,
                   const float* __restrict__ bias, const float* __restrict__ noise,
                   const int* __restrict__ list, const int* __restrict__ cnt,
                   int* __restrict__ bi_arr, float* __restrict__ out)
{
    const int lane = threadIdx.x;
    const int n = *cnt;
#pragma unroll 1
    for (int i0 = blockIdx.x * 4; i0 < n; i0 += 256 * 4) {
        const int t0 = list[i0];
        const int t1 = (i0 + 1 < n) ? list[i0 + 1] : t0;
        const int t2 = (i0 + 2 < n) ? list[i0 + 2] : t0;
        const int t3 = (i0 + 3 < n) ? list[i0 + 3] : t0;
        const float* r0 = A + (size_t)t0 * DM;
        const float* r1 = A + (size_t)t1 * DM;
        const float* r2 = A + (size_t)t2 * DM;
        const float* r3 = A + (size_t)t3 * DM;
        float a0 = 0.f, a1 = 0.f, a2 = 0.f, a3 = 0.f;
#pragma unroll 4
        for (int k = 0; k < DM; ++k) {
            const float wk = W[(size_t)k * NE + lane];
            a0 = fmaf(r0[k], wk, a0);
            a1 = fmaf(r1[k], wk, a1);
            a2 = fmaf(r2[k], wk, a2);
            a3 = fmaf(r3[k], wk, a3);
        }
        const float bl = bias[lane];
        rescue_finish(t0, a0 + bl + noise[(size_t)t0 * NE + lane] * 0.2f + 0.9f, lane, bi_arr, out);
        rescue_finish(t1, a1 + bl + noise[(size_t)t1 * NE + lane] * 0.2f + 0.9f, lane, bi_arr, out);
        rescue_finish(t2, a2 + bl + noise[(size_t)t2 * NE + lane] * 0.2f + 0.9f, lane, bi_arr, out);
        rescue_finish(t3, a3 + bl + noise[(size_t)t3 * NE + lane] * 0.2f + 0.9f, lane, bi_arr, out);
    }
}

// ---------------------------------------------------------------------------
// rank: stable within-128-block rank + histogram via ballots.
// ---------------------------------------------------------------------------
__global__ __launch_bounds__(64)
void rank_kernel(const int* __restrict__ bi_arr, int* __restrict__ pk,
                 int* __restrict__ histg)
{
    const int b    = blockIdx.x;
    const int lane = threadIdx.x;
    const uint64_t below = (1ull << lane) - 1ull;
    const int t0 = b * 128;
    const int b0 = bi_arr[t0 + lane];
    const int b1 = bi_arr[t0 + 64 + lane];
    int lr0 = 0, lr1 = 0, h0 = 0, h1 = 0, h0my = 0;
#pragma unroll 1
    for (int e = 0; e < NE; ++e) {
        const uint64_t m0 = __ballot(b0 == e);
        const uint64_t m1 = __ballot(b1 == e);
        if (b0 == e)   lr0 = (int)__popcll(m0 & below);
        if (b1 == e) { lr1 = (int)__popcll(m1 & below); h0my = (int)__popcll(m0); }
        if (lane == e) { h0 = (int)__popcll(m0); h1 = (int)__popcll(m1); }
    }
    pk[t0 + lane]      = b0 | (lr0 << 6);
    pk[t0 + 64 + lane] = b1 | ((lr1 + h0my) << 6);
    histg[b * NE + lane] = h0 + h1;
}

// ---------------------------------------------------------------------------
// scan / loss / finalize (proven in R5/R8)
// ---------------------------------------------------------------------------
__global__ __launch_bounds__(256)
void scan_kernel(int* __restrict__ hist, const float* __restrict__ colpart,
                 int* __restrict__ totals, float* __restrict__ colsums)
{
    __shared__ int   wtot[4];
    __shared__ float wcs[4];
    const int e = blockIdx.x, t = threadIdx.x, lane = t & 63, w = t >> 6;

    int h[4]; int s = 0; float csl = 0.f;
#pragma unroll
    for (int i = 0; i < 4; ++i) {
        h[i] = hist[(t * 4 + i) * NE + e];
        csl += colpart[(t * 4 + i) * NE + e];
        s   += h[i];
    }
    int inc = s;
#pragma unroll
    for (int d = 1; d < 64; d <<= 1) {
        const int v = __shfl_up(inc, d, 64);
        if (lane >= d) inc += v;
    }
    float wsum = csl;
#pragma unroll
    for (int m = 32; m; m >>= 1) wsum += __shfl_xor(wsum, m, 64);
    if (lane == 63) wtot[w] = inc;
    if (lane == 0)  wcs[w]  = wsum;
    __syncthreads();

    int base = 0;
#pragma unroll
    for (int ww = 0; ww < 4; ++ww) base += (ww < w) ? wtot[ww] : 0;
    int run = base + inc - s;
#pragma unroll
    for (int i = 0; i < 4; ++i) { hist[(t * 4 + i) * NE + e] = run; run += h[i]; }

    if (t == 0) {
        totals[e]  = wtot[0] + wtot[1] + wtot[2] + wtot[3];
        colsums[e] = wcs[0] + wcs[1] + wcs[2] + wcs[3];
    }
}

__global__ void loss_kernel(const int* __restrict__ totals,
                            const float* __restrict__ colsums,
                            float* __restrict__ out)
{
    const int e   = threadIdx.x;
    const int tot = totals[e];
    const float cnt = (float)((tot < CAP) ? tot : CAP);
    float nv = cnt, contrib = cnt * colsums[e];
#pragma unroll
    for (int m = 32; m; m >>= 1) {
        nv      += __shfl_xor(nv, m, 64);
        contrib += __shfl_xor(contrib, m, 64);
    }
    if (e == 0) out[2 * NTOK] = 64.0f * contrib / (nv * nv);
}

__global__ void finalize_kernel(const int* __restrict__ pk, const int* __restrict__ offs,
                                float* __restrict__ out)
{
    const int i = blockIdx.x * 256 + threadIdx.x;
    const int v = pk[i];
    const int e = v & 63;
    const int r = (v >> 6) + offs[(i >> 7) * NE + e];
    out[i] = (r < CAP) ? (float)e : -1.0f;
}

extern "C" void kernel_launch(void* const* d_in, const int* in_sizes, int n_in,
                              void* d_out, int out_size, void* d_ws, size_t ws_size,
                              hipStream_t stream)
{
    (void)in_sizes; (void)n_in; (void)out_size; (void)ws_size;
    const float* A     = (const float*)d_in[0];
    const float* W     = (const float*)d_in[1];
    const float* bias  = (const float*)d_in[2];
    const float* noise = (const float*)d_in[3];
    float* out = (float*)d_out;

    char* ws = (char*)d_ws;
    int*   bi_arr  = (int*)ws;                         // 512 KB
    int*   list    = (int*)(ws + 524288);              // 512 KB (gate->rescue)
    int*   pk      = (int*)(ws + 524288);              // aliased: rank(after rescue)->finalize
    int*   histg   = (int*)(ws + 1048576);             // 256 KB
    float* colpart = (float*)(ws + 1310720);           // 256 KB
    int*   totals  = (int*)(ws + 1572864);             // 256 B
    float* colsums = (float*)(ws + 1573120);           // 256 B
    int*   cnt     = (int*)(ws + 1573376);             // 4 B
    uint4* Wp      = (uint4*)(ws + 1576960);           // 256 KB (2 bf16 planes, frag order)

    wprep_kernel<<<NCHUNK, 256, 0, stream>>>(W, Wp, cnt);
    gate_kernel<<<NBLK, 256, 0, stream>>>(A, Wp, bias, noise, out, bi_arr, list, cnt, colpart);
    rescue_kernel<<<256, 64, 0, stream>>>(A, W, bias, noise, list, cnt, bi_arr, out);
    rank_kernel<<<NBLK, 64, 0, stream>>>(bi_arr, pk, histg);
    scan_kernel<<<NE, 256, 0, stream>>>(histg, colpart, totals, colsums);
    loss_kernel<<<1, 64, 0, stream>>>(totals, colsums, out);
    finalize_kernel<<<NTOK / 256, 256, 0, stream>>>(pk, histg, out);
}

// Round 10
// 323.016 us; speedup vs baseline: 1.2395x; 1.0023x over previous
//
#include <hip/hip_runtime.h>
#include <stdint.h>

#define NTOK   131072
#define DM     1024
#define NE     64
#define TB     128        // tokens per gate block
#define NBLK   1024       // NTOK / TB
#define BK     32         // K chunk
#define NCHUNK 32         // DM / BK
#define CAP    2458       // ceil(1.2 * 131072 / 64)
#define TAU    0.005f     // rescue threshold: >> ~1e-4 2-plane split error

typedef __attribute__((ext_vector_type(8))) short bf16x8;
typedef __attribute__((ext_vector_type(4))) float f32x4;

union Frag { bf16x8 v; uint32_t w[4]; uint4 q; unsigned short u[8]; };

// RNE fp32 -> bf16 bits (wprep only)
__device__ __forceinline__ unsigned short f2bf_rne(float x) {
    uint32_t u = __float_as_uint(x);
    u += 0x7FFFu + ((u >> 16) & 1u);
    return (unsigned short)(u >> 16);
}
__device__ __forceinline__ float bf2f(unsigned short h) {
    return __uint_as_float(((uint32_t)h) << 16);
}

// global -> LDS direct (16B/lane; gptr is the PER-LANE source address,
// LDS dest = wave-uniform base + lane*16)
__device__ __forceinline__ void gload_lds16(const float* g, float* l) {
    __builtin_amdgcn_global_load_lds(
        (const __attribute__((address_space(1))) void*)g,
        (__attribute__((address_space(3))) void*)l, 16, 0, 0);
}

// ---------------------------------------------------------------------------
// wprep: split W (1024x64 fp32) into 2 bf16 planes in MFMA B-frag order.
// Wp[(c*8 + t*2 + p)*64 + l]: col = t*16+(l&15), k = c*32+(l>>4)*8+j.
// Also zeroes the rescue counter (runs before gate on the stream).
// ---------------------------------------------------------------------------
__global__ __launch_bounds__(256)
void wprep_kernel(const float* __restrict__ W, uint4* __restrict__ Wp, int* __restrict__ cnt)
{
    if (blockIdx.x == 0 && threadIdx.x == 0) *cnt = 0;
    const int c = blockIdx.x;          // k-chunk 0..31
    const int t = threadIdx.x >> 6;    // n-tile 0..3
    const int l = threadIdx.x & 63;
    Frag p1, p2;
#pragma unroll
    for (int j = 0; j < 8; ++j) {
        const float wv = W[(size_t)(c * 32 + (l >> 4) * 8 + j) * NE + t * 16 + (l & 15)];
        const unsigned short h1 = f2bf_rne(wv);
        const unsigned short h2 = f2bf_rne(wv - bf2f(h1));
        p1.u[j] = h1; p2.u[j] = h2;
    }
    uint4* base = Wp + (size_t)(c * 8 + t * 2) * 64;
    base[0 * 64 + l] = p1.q;
    base[1 * 64 + l] = p2.q;
}

// 2-plane split of 8 fp32 via packed HW convert (rounding-mode agnostic:
// the residual subtraction is exact for any rounding of the first plane).
struct ASet { float4 p00, p01, p10, p11; };

__device__ __forceinline__ void splitA(const float4& P0, const float4& P1,
                                       Frag& A1, Frag& A2)
{
    const float xs[8] = {P0.x, P0.y, P0.z, P0.w, P1.x, P1.y, P1.z, P1.w};
#pragma unroll
    for (int j = 0; j < 4; ++j) {
        uint32_t p1, p2;
        asm("v_cvt_pk_bf16_f32 %0, %1, %2" : "=v"(p1) : "v"(xs[2*j]), "v"(xs[2*j+1]));
        const float f0 = __uint_as_float(p1 << 16);
        const float f1 = __uint_as_float(p1 & 0xffff0000u);
        const float r0 = xs[2*j] - f0;
        const float r1 = xs[2*j+1] - f1;
        asm("v_cvt_pk_bf16_f32 %0, %1, %2" : "=v"(p2) : "v"(r0), "v"(r1));
        A1.w[j] = p1; A2.w[j] = p2;
    }
}

// ---------------------------------------------------------------------------
// gate_kernel (R10, occupancy-first MFMA): 4 waves x 32 tokens, 64 experts.
// R9 post-mortem: 2 waves/SIMD + 220-VGPR reg pipeline = ~95% stall. R10:
//   - B staged once per block in LDS dbuf (kills 4x redundant loads + 96 VGPR)
//   - A direct-to-reg, depth-1 double buffer (2 named sets, static idx)
//   - R5's 2-barrier counted-vmcnt(6) schedule (c+1 loads fly across barrier)
//   - target <=128 VGPR -> 4 waves/SIMD; latency hidden by TLP across blocks
// 3-term split MFMA: a·w ~= a1w1 + a1w2 + a2w1 (err ~1e-4 << TAU/2).
// ---------------------------------------------------------------------------
__global__ __launch_bounds__(256, 4)
void gate_kernel(const float* __restrict__ A, const uint4* __restrict__ Wp,
                 const float* __restrict__ bias, const float* __restrict__ noise,
                 float* __restrict__ out, int* __restrict__ bi_arr,
                 int* __restrict__ list, int* __restrict__ cnt,
                 float* __restrict__ colpart)
{
    __shared__ uint4 bLds[2][8][64];   // 16 KB: B frags, chunk dbuf
    __shared__ float wcol[4][NE];

    const int tid  = threadIdx.x;
    const int lane = tid & 63;
    const int w    = __builtin_amdgcn_readfirstlane(tid >> 6);
    const int blk  = blockIdx.x;
    const int tokBase = blk * TB;
    const int g    = lane >> 4;
    const int e16  = lane & 15;

    f32x4 acc[2][4];
#pragma unroll
    for (int mt = 0; mt < 2; ++mt)
#pragma unroll
        for (int nt = 0; nt < 4; ++nt)
            acc[mt][nt] = (f32x4){0.f, 0.f, 0.f, 0.f};

    // A rows owned by this lane: mt=0 -> row w*32+e16, mt=1 -> +16
    const float* aRow0 = A + (size_t)(tokBase + w * 32 + e16) * DM + g * 8;
    const float* aRow1 = aRow0 + (size_t)16 * DM;

#define STAGEB(c) {                                                           \
        gload_lds16((const float*)(Wp + ((size_t)(c) * 8 + w * 2) * 64 + lane),      \
                    (float*)&bLds[(c) & 1][w * 2][0]);                        \
        gload_lds16((const float*)(Wp + ((size_t)(c) * 8 + w * 2 + 1) * 64 + lane),  \
                    (float*)&bLds[(c) & 1][w * 2 + 1][0]);                    \
    }
#define LOADA(c, S)  { S.p00 = *(const float4*)(aRow0 + (c) * BK);       \
                       S.p01 = *(const float4*)(aRow0 + (c) * BK + 4);   \
                       S.p10 = *(const float4*)(aRow1 + (c) * BK);       \
                       S.p11 = *(const float4*)(aRow1 + (c) * BK + 4); }
#define COMPUTE(c, AS) {                                                 \
        Frag a1_[2], a2_[2];                                             \
        splitA(AS.p00, AS.p01, a1_[0], a2_[0]);                          \
        splitA(AS.p10, AS.p11, a1_[1], a2_[1]);                          \
        _Pragma("unroll")                                                \
        for (int nt_ = 0; nt_ < 4; ++nt_) {                              \
            Frag b1_, b2_;                                               \
            b1_.q = bLds[(c) & 1][nt_ * 2][lane];                        \
            b2_.q = bLds[(c) & 1][nt_ * 2 + 1][lane];                    \
            _Pragma("unroll")                                            \
            for (int mt_ = 0; mt_ < 2; ++mt_) {                          \
                f32x4 d_ = acc[mt_][nt_];                                \
                d_ = __builtin_amdgcn_mfma_f32_16x16x32_bf16(a1_[mt_].v, b1_.v, d_, 0, 0, 0); \
                d_ = __builtin_amdgcn_mfma_f32_16x16x32_bf16(a1_[mt_].v, b2_.v, d_, 0, 0, 0); \
                d_ = __builtin_amdgcn_mfma_f32_16x16x32_bf16(a2_[mt_].v, b1_.v, d_, 0, 0, 0); \
                acc[mt_][nt_] = d_;                                      \
            }                                                            \
        }                                                                \
    }
#define CHUNK_BODY(c, AS_CUR, AS_NXT) {                                  \
        __builtin_amdgcn_s_barrier();            /* B1: WAR fence */     \
        asm volatile("" ::: "memory");                                   \
        if ((c) + 1 < NCHUNK) {                                          \
            STAGEB((c) + 1)                                              \
            LOADA((c) + 1, AS_NXT)                                       \
            asm volatile("s_waitcnt vmcnt(6)" ::: "memory");             \
        } else {                                                         \
            asm volatile("s_waitcnt vmcnt(0)" ::: "memory");             \
        }                                                                \
        __builtin_amdgcn_sched_barrier(0);                               \
        __builtin_amdgcn_s_barrier();            /* B2: chunk c ready */ \
        asm volatile("" ::: "memory");                                   \
        COMPUTE(c, AS_CUR)                                               \
    }

    ASet As0, As1;
    STAGEB(0) LOADA(0, As0)          // prologue: 6 outstanding
#pragma unroll 1
    for (int cc = 0; cc < NCHUNK; cc += 2) {
        CHUNK_BODY(cc,     As0, As1)
        CHUNK_BODY(cc + 1, As1, As0)
    }
#undef CHUNK_BODY
#undef COMPUTE
#undef LOADA
#undef STAGEB

    // ---- epilogue: bias+noise, per-token argmax/softmax, rescue-list ----
    // C/D: token = w*32 + mt*16 + g*4 + r, expert = nt*16 + e16 (m89 layout)
#pragma unroll
    for (int mt = 0; mt < 2; ++mt)
#pragma unroll
        for (int r = 0; r < 4; ++r) {
            const int T = tokBase + w * 32 + mt * 16 + g * 4 + r;
#pragma unroll
            for (int nt = 0; nt < 4; ++nt) {
                const float nz = noise[(size_t)T * NE + nt * 16 + e16];
                acc[mt][nt][r] += bias[nt * 16 + e16] + nz * 0.2f + 0.9f;
            }
        }

    float cw[4] = {0.f, 0.f, 0.f, 0.f};
#pragma unroll
    for (int mt = 0; mt < 2; ++mt)
#pragma unroll
        for (int r = 0; r < 4; ++r) {
            const int T = tokBase + w * 32 + mt * 16 + g * 4 + r;
            float raw[4];
#pragma unroll
            for (int nt = 0; nt < 4; ++nt) raw[nt] = acc[mt][nt][r];

            float v = raw[0]; int be = e16;
#pragma unroll
            for (int nt = 1; nt < 4; ++nt)
                if (raw[nt] > v) { v = raw[nt]; be = nt * 16 + e16; }
#pragma unroll
            for (int m = 1; m <= 8; m <<= 1) {
                const float vo = __shfl_xor(v, m, 64);
                const int   eo = __shfl_xor(be, m, 64);
                if (vo > v || (vo == v && eo < be)) { v = vo; be = eo; }
            }
            float m2 = -1e30f;                          // runner-up
#pragma unroll
            for (int nt = 0; nt < 4; ++nt)
                if (nt * 16 + e16 != be && raw[nt] > m2) m2 = raw[nt];
#pragma unroll
            for (int m = 1; m <= 8; m <<= 1)
                m2 = fmaxf(m2, __shfl_xor(m2, m, 64));

            float d = 0.f, pr[4];
#pragma unroll
            for (int nt = 0; nt < 4; ++nt) { pr[nt] = __expf(raw[nt] - v); d += pr[nt]; }
#pragma unroll
            for (int m = 1; m <= 8; m <<= 1) d += __shfl_xor(d, m, 64);
            const float inv = 1.0f / d;
#pragma unroll
            for (int nt = 0; nt < 4; ++nt) cw[nt] += pr[nt] * inv;

            if (e16 == mt * 4 + r) {                    // one writer per (g,mt,r)
                out[NTOK + T] = inv;
                bi_arr[T]     = be;
                if (v - m2 < TAU) {                     // borderline -> rescue list
                    const int s = atomicAdd(cnt, 1);
                    list[s] = T;
                }
            }
        }

#pragma unroll
    for (int nt = 0; nt < 4; ++nt) {
        cw[nt] += __shfl_xor(cw[nt], 16, 64);
        cw[nt] += __shfl_xor(cw[nt], 32, 64);
    }
    if (lane < 16) {
#pragma unroll
        for (int nt = 0; nt < 4; ++nt) wcol[w][nt * 16 + lane] = cw[nt];
    }
    __syncthreads();
    if (tid < NE)
        colpart[blk * NE + tid] = wcol[0][tid] + wcol[1][tid] + wcol[2][tid] + wcol[3][tid];
}

// ---------------------------------------------------------------------------
// rescue: recompute listed tokens with the bit-identical R5 sequential-fmaf
// chain (k ascending). 4 tokens per wave-batch = 4 independent ILP chains.
// ---------------------------------------------------------------------------
__device__ __forceinline__ void rescue_finish(int t, float sc, int lane,
                                              int* bi_arr, float* out)
{
    float v = sc; int be = lane;
#pragma unroll
    for (int m = 1; m <= 32; m <<= 1) {
        const float vo = __shfl_xor(v, m, 64);
        const int   eo = __shfl_xor(be, m, 64);
        if (vo > v || (vo == v && eo < be)) { v = vo; be = eo; }
    }
    float d = __expf(sc - v);
#pragma unroll
    for (int m = 1; m <= 32; m <<= 1) d += __shfl_xor(d, m, 64);
    if (lane == 0) { bi_arr[t] = be; out[NTOK + t] = 1.0f / d; }
}

__global__ __launch_bounds__(64)
void rescue_kernel(const float* __restrict__ A, const float* __restrict__ W,
                   const float* __restrict__ bias, const float* __restrict__ noise,
                   const int* __restrict__ list, const int* __restrict__ cnt,
                   int* __restrict__ bi_arr, float* __restrict__ out)
{
    const int lane = threadIdx.x;
    const int n = *cnt;
#pragma unroll 1
    for (int i0 = blockIdx.x * 4; i0 < n; i0 += 256 * 4) {
        const int t0 = list[i0];
        const int t1 = (i0 + 1 < n) ? list[i0 + 1] : t0;
        const int t2 = (i0 + 2 < n) ? list[i0 + 2] : t0;
        const int t3 = (i0 + 3 < n) ? list[i0 + 3] : t0;
        const float* r0 = A + (size_t)t0 * DM;
        const float* r1 = A + (size_t)t1 * DM;
        const float* r2 = A + (size_t)t2 * DM;
        const float* r3 = A + (size_t)t3 * DM;
        float a0 = 0.f, a1 = 0.f, a2 = 0.f, a3 = 0.f;
#pragma unroll 4
        for (int k = 0; k < DM; ++k) {
            const float wk = W[(size_t)k * NE + lane];
            a0 = fmaf(r0[k], wk, a0);
            a1 = fmaf(r1[k], wk, a1);
            a2 = fmaf(r2[k], wk, a2);
            a3 = fmaf(r3[k], wk, a3);
        }
        const float bl = bias[lane];
        rescue_finish(t0, a0 + bl + noise[(size_t)t0 * NE + lane] * 0.2f + 0.9f, lane, bi_arr, out);
        rescue_finish(t1, a1 + bl + noise[(size_t)t1 * NE + lane] * 0.2f + 0.9f, lane, bi_arr, out);
        rescue_finish(t2, a2 + bl + noise[(size_t)t2 * NE + lane] * 0.2f + 0.9f, lane, bi_arr, out);
        rescue_finish(t3, a3 + bl + noise[(size_t)t3 * NE + lane] * 0.2f + 0.9f, lane, bi_arr, out);
    }
}

// ---------------------------------------------------------------------------
// rank: stable within-128-block rank + histogram via ballots.
// ---------------------------------------------------------------------------
__global__ __launch_bounds__(64)
void rank_kernel(const int* __restrict__ bi_arr, int* __restrict__ pk,
                 int* __restrict__ histg)
{
    const int b    = blockIdx.x;
    const int lane = threadIdx.x;
    const uint64_t below = (1ull << lane) - 1ull;
    const int t0 = b * 128;
    const int b0 = bi_arr[t0 + lane];
    const int b1 = bi_arr[t0 + 64 + lane];
    int lr0 = 0, lr1 = 0, h0 = 0, h1 = 0, h0my = 0;
#pragma unroll 1
    for (int e = 0; e < NE; ++e) {
        const uint64_t m0 = __ballot(b0 == e);
        const uint64_t m1 = __ballot(b1 == e);
        if (b0 == e)   lr0 = (int)__popcll(m0 & below);
        if (b1 == e) { lr1 = (int)__popcll(m1 & below); h0my = (int)__popcll(m0); }
        if (lane == e) { h0 = (int)__popcll(m0); h1 = (int)__popcll(m1); }
    }
    pk[t0 + lane]      = b0 | (lr0 << 6);
    pk[t0 + 64 + lane] = b1 | ((lr1 + h0my) << 6);
    histg[b * NE + lane] = h0 + h1;
}

// ---------------------------------------------------------------------------
// scan / loss / finalize (proven in R5/R8/R9)
// ---------------------------------------------------------------------------
__global__ __launch_bounds__(256)
void scan_kernel(int* __restrict__ hist, const float* __restrict__ colpart,
                 int* __restrict__ totals, float* __restrict__ colsums)
{
    __shared__ int   wtot[4];
    __shared__ float wcs[4];
    const int e = blockIdx.x, t = threadIdx.x, lane = t & 63, w = t >> 6;

    int h[4]; int s = 0; float csl = 0.f;
#pragma unroll
    for (int i = 0; i < 4; ++i) {
        h[i] = hist[(t * 4 + i) * NE + e];
        csl += colpart[(t * 4 + i) * NE + e];
        s   += h[i];
    }
    int inc = s;
#pragma unroll
    for (int d = 1; d < 64; d <<= 1) {
        const int v = __shfl_up(inc, d, 64);
        if (lane >= d) inc += v;
    }
    float wsum = csl;
#pragma unroll
    for (int m = 32; m; m >>= 1) wsum += __shfl_xor(wsum, m, 64);
    if (lane == 63) wtot[w] = inc;
    if (lane == 0)  wcs[w]  = wsum;
    __syncthreads();

    int base = 0;
#pragma unroll
    for (int ww = 0; ww < 4; ++ww) base += (ww < w) ? wtot[ww] : 0;
    int run = base + inc - s;
#pragma unroll
    for (int i = 0; i < 4; ++i) { hist[(t * 4 + i) * NE + e] = run; run += h[i]; }

    if (t == 0) {
        totals[e]  = wtot[0] + wtot[1] + wtot[2] + wtot[3];
        colsums[e] = wcs[0] + wcs[1] + wcs[2] + wcs[3];
    }
}

__global__ void loss_kernel(const int* __restrict__ totals,
                            const float* __restrict__ colsums,
                            float* __restrict__ out)
{
    const int e   = threadIdx.x;
    const int tot = totals[e];
    const float cnt = (float)((tot < CAP) ? tot : CAP);
    float nv = cnt, contrib = cnt * colsums[e];
#pragma unroll
    for (int m = 32; m; m >>= 1) {
        nv      += __shfl_xor(nv, m, 64);
        contrib += __shfl_xor(contrib, m, 64);
    }
    if (e == 0) out[2 * NTOK] = 64.0f * contrib / (nv * nv);
}

__global__ void finalize_kernel(const int* __restrict__ pk, const int* __restrict__ offs,
                                float* __restrict__ out)
{
    const int i = blockIdx.x * 256 + threadIdx.x;
    const int v = pk[i];
    const int e = v & 63;
    const int r = (v >> 6) + offs[(i >> 7) * NE + e];
    out[i] = (r < CAP) ? (float)e : -1.0f;
}

extern "C" void kernel_launch(void* const* d_in, const int* in_sizes, int n_in,
                              void* d_out, int out_size, void* d_ws, size_t ws_size,
                              hipStream_t stream)
{
    (void)in_sizes; (void)n_in; (void)out_size; (void)ws_size;
    const float* A     = (const float*)d_in[0];
    const float* W     = (const float*)d_in[1];
    const float* bias  = (const float*)d_in[2];
    const float* noise = (const float*)d_in[3];
    float* out = (float*)d_out;

    char* ws = (char*)d_ws;
    int*   bi_arr  = (int*)ws;                         // 512 KB
    int*   list    = (int*)(ws + 524288);              // 512 KB (gate->rescue)
    int*   pk      = (int*)(ws + 524288);              // aliased: rank(after rescue)->finalize
    int*   histg   = (int*)(ws + 1048576);             // 256 KB
    float* colpart = (float*)(ws + 1310720);           // 256 KB
    int*   totals  = (int*)(ws + 1572864);             // 256 B
    float* colsums = (float*)(ws + 1573120);           // 256 B
    int*   cnt     = (int*)(ws + 1573376);             // 4 B
    uint4* Wp      = (uint4*)(ws + 1576960);           // 256 KB (2 bf16 planes, frag order)

    wprep_kernel<<<NCHUNK, 256, 0, stream>>>(W, Wp, cnt);
    gate_kernel<<<NBLK, 256, 0, stream>>>(A, Wp, bias, noise, out, bi_arr, list, cnt, colpart);
    rescue_kernel<<<256, 64, 0, stream>>>(A, W, bias, noise, list, cnt, bi_arr, out);
    rank_kernel<<<NBLK, 64, 0, stream>>>(bi_arr, pk, histg);
    scan_kernel<<<NE, 256, 0, stream>>>(histg, colpart, totals, colsums);
    loss_kernel<<<1, 64, 0, stream>>>(totals, colsums, out);
    finalize_kernel<<<NTOK / 256, 256, 0, stream>>>(pk, histg, out);
}

// Round 11
// 287.879 us; speedup vs baseline: 1.3908x; 1.1221x over previous
//
#include <hip/hip_runtime.h>
#include <stdint.h>

#define NTOK   131072
#define DM     1024
#define NE     64
#define TB     32         // tokens per gate block (1 wave!)
#define NBLK   4096       // NTOK / TB
#define BK     32         // K chunk (floats)
#define NCHUNK 32         // DM / BK
#define CAP    2458       // ceil(1.2 * 131072 / 64)
#define TAU    0.002f     // rescue threshold: >> ~4e-5 2-plane split error bound

typedef __attribute__((ext_vector_type(8))) short bf16x8;
typedef __attribute__((ext_vector_type(4))) float f32x4;

union Frag { bf16x8 v; uint32_t w[4]; uint4 q; unsigned short u[8]; };

// RNE fp32 -> bf16 bits (wprep only)
__device__ __forceinline__ unsigned short f2bf_rne(float x) {
    uint32_t u = __float_as_uint(x);
    u += 0x7FFFu + ((u >> 16) & 1u);
    return (unsigned short)(u >> 16);
}
__device__ __forceinline__ float bf2f(unsigned short h) {
    return __uint_as_float(((uint32_t)h) << 16);
}

// global -> LDS direct (16B/lane; gptr is the PER-LANE source address,
// LDS dest = wave-uniform base + lane*16)
__device__ __forceinline__ void gload_lds16(const float* g, float* l) {
    __builtin_amdgcn_global_load_lds(
        (const __attribute__((address_space(1))) void*)g,
        (__attribute__((address_space(3))) void*)l, 16, 0, 0);
}

// ---------------------------------------------------------------------------
// wprep: split W (1024x64 fp32) into 2 bf16 planes in MFMA B-frag order.
// Wp[(c*8 + t*2 + p)*64 + l]: col = t*16+(l&15), k = c*32+(l>>4)*8+j.
// Also zeroes the rescue counter.
// ---------------------------------------------------------------------------
__global__ __launch_bounds__(256)
void wprep_kernel(const float* __restrict__ W, uint4* __restrict__ Wp, int* __restrict__ cnt)
{
    if (blockIdx.x == 0 && threadIdx.x == 0) *cnt = 0;
    const int c = blockIdx.x;          // k-chunk 0..31
    const int t = threadIdx.x >> 6;    // n-tile 0..3
    const int l = threadIdx.x & 63;
    Frag p1, p2;
#pragma unroll
    for (int j = 0; j < 8; ++j) {
        const float wv = W[(size_t)(c * 32 + (l >> 4) * 8 + j) * NE + t * 16 + (l & 15)];
        const unsigned short h1 = f2bf_rne(wv);
        const unsigned short h2 = f2bf_rne(wv - bf2f(h1));
        p1.u[j] = h1; p2.u[j] = h2;
    }
    uint4* base = Wp + (size_t)(c * 8 + t * 2) * 64;
    base[0 * 64 + l] = p1.q;
    base[1 * 64 + l] = p2.q;
}

// 2-plane split of 8 fp32 via packed HW convert (rounding-mode agnostic:
// the residual subtraction is exact for any rounding of the first plane).
__device__ __forceinline__ void splitA(const float4& P0, const float4& P1,
                                       Frag& A1, Frag& A2)
{
    const float xs[8] = {P0.x, P0.y, P0.z, P0.w, P1.x, P1.y, P1.z, P1.w};
#pragma unroll
    for (int j = 0; j < 4; ++j) {
        uint32_t p1, p2;
        asm("v_cvt_pk_bf16_f32 %0, %1, %2" : "=v"(p1) : "v"(xs[2*j]), "v"(xs[2*j+1]));
        const float f0 = __uint_as_float(p1 << 16);
        const float f1 = __uint_as_float(p1 & 0xffff0000u);
        const float r0 = xs[2*j] - f0;
        const float r1 = xs[2*j+1] - f1;
        asm("v_cvt_pk_bf16_f32 %0, %1, %2" : "=v"(p2) : "v"(r0), "v"(r1));
        A1.w[j] = p1; A2.w[j] = p2;
    }
}

// ---------------------------------------------------------------------------
// gate_kernel (R11): ONE WAVE PER BLOCK, 32 tokens, all 64 experts. Zero
// barriers; wave-private LDS dbuf; per-wave counted vmcnt(12). R9/R10
// post-mortem: block-wide barriers (or 2-wave reg pipelines) exposed ~900cy
// HBM latency on every chunk, convoying waves. Here 13 independent 1-wave
// blocks/CU phase freely — some wave is always compute-ready (attn-§B
// structure). 12 stage ops/chunk (4 A-rows-of-8 + 8 B-frag-rows), in-order
// vmcnt => vmcnt(12) retires exactly chunk c with c+1 in flight.
// A tile XOR-swizzled (rule #21): linear LDS dest, pre-swizzled global src,
// same XOR on the read side -> conflict-free ds_read_b128.
// 3-term split MFMA: a.w ~= a1w1 + a1w2 + a2w1 (err ~2e-5 << TAU).
// ---------------------------------------------------------------------------
__global__ __launch_bounds__(64, 4)
void gate_kernel(const float* __restrict__ A, const uint4* __restrict__ Wp,
                 const float* __restrict__ bias, const float* __restrict__ noise,
                 float* __restrict__ out, int* __restrict__ bi_arr,
                 int* __restrict__ list, int* __restrict__ cnt,
                 float* __restrict__ colpart)
{
    __shared__ __align__(16) float aLds[2][TB][BK];  // 8 KB, swizzled slots
    __shared__ __align__(16) uint4 bLds[2][8][64];   // 4 KB, frag rows

    const int lane = threadIdx.x;
    const int blk  = blockIdx.x;
    const int tokBase = blk * TB;
    const int g    = lane >> 4;
    const int e16  = lane & 15;

    f32x4 acc[2][4];
#pragma unroll
    for (int mt = 0; mt < 2; ++mt)
#pragma unroll
        for (int nt = 0; nt < 4; ++nt)
            acc[mt][nt] = (f32x4){0.f, 0.f, 0.f, 0.f};

    // A staging source: row r stores logical 16B-slot s at phys s^(r&7);
    // lane covers row q*8+(lane>>3), phys slot lane&7.
    const int sl = (lane & 7) ^ ((lane >> 3) & 7);
    const float* aSrc = A + (size_t)(tokBase + (lane >> 3)) * DM + sl * 4;

#define STAGE(c, b) {                                                         \
        _Pragma("unroll")                                                     \
        for (int q_ = 0; q_ < 4; ++q_)                                        \
            gload_lds16(aSrc + (size_t)q_ * 8 * DM + (c) * BK,                \
                        &aLds[b][q_ * 8][0]);                                 \
        _Pragma("unroll")                                                     \
        for (int u_ = 0; u_ < 8; ++u_)                                        \
            gload_lds16((const float*)(Wp + ((size_t)(c) * 8 + u_) * 64 + lane), \
                        (float*)&bLds[b][u_][0]);                             \
    }
#define COMPUTE(b) {                                                          \
        Frag a1_[2], a2_[2];                                                  \
        _Pragma("unroll")                                                     \
        for (int mt_ = 0; mt_ < 2; ++mt_) {                                   \
            const float* rp_ = &aLds[b][mt_ * 16 + e16][0];                   \
            const float4 x0_ = *(const float4*)(rp_ + (((2*g)   ^ (e16 & 7)) << 2)); \
            const float4 x1_ = *(const float4*)(rp_ + (((2*g+1) ^ (e16 & 7)) << 2)); \
            splitA(x0_, x1_, a1_[mt_], a2_[mt_]);                             \
        }                                                                     \
        _Pragma("unroll")                                                     \
        for (int nt_ = 0; nt_ < 4; ++nt_) {                                   \
            Frag b1_, b2_;                                                    \
            b1_.q = bLds[b][nt_ * 2][lane];                                   \
            b2_.q = bLds[b][nt_ * 2 + 1][lane];                               \
            _Pragma("unroll")                                                 \
            for (int mt_ = 0; mt_ < 2; ++mt_) {                               \
                f32x4 d_ = acc[mt_][nt_];                                     \
                d_ = __builtin_amdgcn_mfma_f32_16x16x32_bf16(a1_[mt_].v, b1_.v, d_, 0, 0, 0); \
                d_ = __builtin_amdgcn_mfma_f32_16x16x32_bf16(a1_[mt_].v, b2_.v, d_, 0, 0, 0); \
                d_ = __builtin_amdgcn_mfma_f32_16x16x32_bf16(a2_[mt_].v, b1_.v, d_, 0, 0, 0); \
                acc[mt_][nt_] = d_;                                           \
            }                                                                 \
        }                                                                     \
    }

    STAGE(0, 0)
#pragma unroll 1
    for (int cc = 0; cc < NCHUNK; cc += 2) {
        STAGE(cc + 1, 1)                       // cc+1 <= 31 always (cc <= 30)
        asm volatile("s_waitcnt vmcnt(12)" ::: "memory");   // chunk cc landed
        __builtin_amdgcn_sched_barrier(0);
        COMPUTE(0)
        if (cc + 2 < NCHUNK) {
            STAGE(cc + 2, 0)
            asm volatile("s_waitcnt vmcnt(12)" ::: "memory");
        } else {
            asm volatile("s_waitcnt vmcnt(0)" ::: "memory");
        }
        __builtin_amdgcn_sched_barrier(0);
        COMPUTE(1)
    }
#undef COMPUTE
#undef STAGE

    // ---- epilogue: bias+noise, per-token argmax/softmax, rescue-list ----
    // C/D: token = mt*16 + g*4 + r (row), expert = nt*16 + e16 (col) [m89]
#pragma unroll
    for (int mt = 0; mt < 2; ++mt)
#pragma unroll
        for (int r = 0; r < 4; ++r) {
            const int T = tokBase + mt * 16 + g * 4 + r;
#pragma unroll
            for (int nt = 0; nt < 4; ++nt) {
                const float nz = noise[(size_t)T * NE + nt * 16 + e16];
                acc[mt][nt][r] += bias[nt * 16 + e16] + nz * 0.2f + 0.9f;
            }
        }

    float cw[4] = {0.f, 0.f, 0.f, 0.f};
#pragma unroll
    for (int mt = 0; mt < 2; ++mt)
#pragma unroll
        for (int r = 0; r < 4; ++r) {
            const int T = tokBase + mt * 16 + g * 4 + r;
            float raw[4];
#pragma unroll
            for (int nt = 0; nt < 4; ++nt) raw[nt] = acc[mt][nt][r];

            float v = raw[0]; int be = e16;
#pragma unroll
            for (int nt = 1; nt < 4; ++nt)
                if (raw[nt] > v) { v = raw[nt]; be = nt * 16 + e16; }
#pragma unroll
            for (int m = 1; m <= 8; m <<= 1) {
                const float vo = __shfl_xor(v, m, 64);
                const int   eo = __shfl_xor(be, m, 64);
                if (vo > v || (vo == v && eo < be)) { v = vo; be = eo; }
            }
            float m2 = -1e30f;                          // runner-up
#pragma unroll
            for (int nt = 0; nt < 4; ++nt)
                if (nt * 16 + e16 != be && raw[nt] > m2) m2 = raw[nt];
#pragma unroll
            for (int m = 1; m <= 8; m <<= 1)
                m2 = fmaxf(m2, __shfl_xor(m2, m, 64));

            float d = 0.f, pr[4];
#pragma unroll
            for (int nt = 0; nt < 4; ++nt) { pr[nt] = __expf(raw[nt] - v); d += pr[nt]; }
#pragma unroll
            for (int m = 1; m <= 8; m <<= 1) d += __shfl_xor(d, m, 64);
            const float inv = 1.0f / d;
#pragma unroll
            for (int nt = 0; nt < 4; ++nt) cw[nt] += pr[nt] * inv;

            if (e16 == mt * 4 + r) {                    // one writer per (g,mt,r)
                out[NTOK + T] = inv;
                bi_arr[T]     = be;
                if (v - m2 < TAU) {                     // borderline -> rescue
                    const int s = atomicAdd(cnt, 1);
                    list[s] = T;
                }
            }
        }

    // per-expert column sums over this wave's 32 tokens
#pragma unroll
    for (int nt = 0; nt < 4; ++nt) {
        cw[nt] += __shfl_xor(cw[nt], 16, 64);
        cw[nt] += __shfl_xor(cw[nt], 32, 64);
    }
    if (lane < 16) {
#pragma unroll
        for (int nt = 0; nt < 4; ++nt)
            colpart[blk * NE + nt * 16 + lane] = cw[nt];
    }
}

// ---------------------------------------------------------------------------
// rescue: recompute listed tokens with the bit-identical R5 sequential-fmaf
// chain (k ascending). fmaf dep-chain = 4cy/link -> ~2 us per quad; loads
// prefetch ahead under unroll.
// ---------------------------------------------------------------------------
__device__ __forceinline__ void rescue_finish(int t, float sc, int lane,
                                              int* bi_arr, float* out)
{
    float v = sc; int be = lane;
#pragma unroll
    for (int m = 1; m <= 32; m <<= 1) {
        const float vo = __shfl_xor(v, m, 64);
        const int   eo = __shfl_xor(be, m, 64);
        if (vo > v || (vo == v && eo < be)) { v = vo; be = eo; }
    }
    float d = __expf(sc - v);
#pragma unroll
    for (int m = 1; m <= 32; m <<= 1) d += __shfl_xor(d, m, 64);
    if (lane == 0) { bi_arr[t] = be; out[NTOK + t] = 1.0f / d; }
}

__global__ __launch_bounds__(64)
void rescue_kernel(const float* __restrict__ A, const float* __restrict__ W,
                   const float* __restrict__ bias, const float* __restrict__ noise,
                   const int* __restrict__ list, const int* __restrict__ cnt,
                   int* __restrict__ bi_arr, float* __restrict__ out)
{
    const int lane = threadIdx.x;
    const int n = *cnt;
#pragma unroll 1
    for (int i0 = blockIdx.x * 4; i0 < n; i0 += 256 * 4) {
        const int t0 = list[i0];
        const int t1 = (i0 + 1 < n) ? list[i0 + 1] : t0;
        const int t2 = (i0 + 2 < n) ? list[i0 + 2] : t0;
        const int t3 = (i0 + 3 < n) ? list[i0 + 3] : t0;
        const float* r0 = A + (size_t)t0 * DM;
        const float* r1 = A + (size_t)t1 * DM;
        const float* r2 = A + (size_t)t2 * DM;
        const float* r3 = A + (size_t)t3 * DM;
        float a0 = 0.f, a1 = 0.f, a2 = 0.f, a3 = 0.f;
#pragma unroll 4
        for (int k = 0; k < DM; ++k) {
            const float wk = W[(size_t)k * NE + lane];
            a0 = fmaf(r0[k], wk, a0);
            a1 = fmaf(r1[k], wk, a1);
            a2 = fmaf(r2[k], wk, a2);
            a3 = fmaf(r3[k], wk, a3);
        }
        const float bl = bias[lane];
        rescue_finish(t0, a0 + bl + noise[(size_t)t0 * NE + lane] * 0.2f + 0.9f, lane, bi_arr, out);
        rescue_finish(t1, a1 + bl + noise[(size_t)t1 * NE + lane] * 0.2f + 0.9f, lane, bi_arr, out);
        rescue_finish(t2, a2 + bl + noise[(size_t)t2 * NE + lane] * 0.2f + 0.9f, lane, bi_arr, out);
        rescue_finish(t3, a3 + bl + noise[(size_t)t3 * NE + lane] * 0.2f + 0.9f, lane, bi_arr, out);
    }
}

// ---------------------------------------------------------------------------
// rank: stable within-128-token-block rank + histogram via ballots.
// ---------------------------------------------------------------------------
__global__ __launch_bounds__(64)
void rank_kernel(const int* __restrict__ bi_arr, int* __restrict__ pk,
                 int* __restrict__ histg)
{
    const int b    = blockIdx.x;
    const int lane = threadIdx.x;
    const uint64_t below = (1ull << lane) - 1ull;
    const int t0 = b * 128;
    const int b0 = bi_arr[t0 + lane];
    const int b1 = bi_arr[t0 + 64 + lane];
    int lr0 = 0, lr1 = 0, h0 = 0, h1 = 0, h0my = 0;
#pragma unroll 1
    for (int e = 0; e < NE; ++e) {
        const uint64_t m0 = __ballot(b0 == e);
        const uint64_t m1 = __ballot(b1 == e);
        if (b0 == e)   lr0 = (int)__popcll(m0 & below);
        if (b1 == e) { lr1 = (int)__popcll(m1 & below); h0my = (int)__popcll(m0); }
        if (lane == e) { h0 = (int)__popcll(m0); h1 = (int)__popcll(m1); }
    }
    pk[t0 + lane]      = b0 | (lr0 << 6);
    pk[t0 + 64 + lane] = b1 | ((lr1 + h0my) << 6);
    histg[b * NE + lane] = h0 + h1;
}

// ---------------------------------------------------------------------------
// scan: per-expert exclusive scan over 1024 rank-block histograms (in-place)
// + per-expert totals and softmax column sums (colpart now 4096 gate blocks).
// ---------------------------------------------------------------------------
__global__ __launch_bounds__(256)
void scan_kernel(int* __restrict__ hist, const float* __restrict__ colpart,
                 int* __restrict__ totals, float* __restrict__ colsums)
{
    __shared__ int   wtot[4];
    __shared__ float wcs[4];
    const int e = blockIdx.x, t = threadIdx.x, lane = t & 63, w = t >> 6;

    int h[4]; int s = 0; float csl = 0.f;
#pragma unroll
    for (int i = 0; i < 4; ++i) {
        h[i] = hist[(t * 4 + i) * NE + e];
        s   += h[i];
    }
#pragma unroll
    for (int i = 0; i < 16; ++i)
        csl += colpart[(t * 16 + i) * NE + e];

    int inc = s;
#pragma unroll
    for (int d = 1; d < 64; d <<= 1) {
        const int v = __shfl_up(inc, d, 64);
        if (lane >= d) inc += v;
    }
    float wsum = csl;
#pragma unroll
    for (int m = 32; m; m >>= 1) wsum += __shfl_xor(wsum, m, 64);
    if (lane == 63) wtot[w] = inc;
    if (lane == 0)  wcs[w]  = wsum;
    __syncthreads();

    int base = 0;
#pragma unroll
    for (int ww = 0; ww < 4; ++ww) base += (ww < w) ? wtot[ww] : 0;
    int run = base + inc - s;
#pragma unroll
    for (int i = 0; i < 4; ++i) { hist[(t * 4 + i) * NE + e] = run; run += h[i]; }

    if (t == 0) {
        totals[e]  = wtot[0] + wtot[1] + wtot[2] + wtot[3];
        colsums[e] = wcs[0] + wcs[1] + wcs[2] + wcs[3];
    }
}

__global__ void loss_kernel(const int* __restrict__ totals,
                            const float* __restrict__ colsums,
                            float* __restrict__ out)
{
    const int e   = threadIdx.x;
    const int tot = totals[e];
    const float cnt = (float)((tot < CAP) ? tot : CAP);
    float nv = cnt, contrib = cnt * colsums[e];
#pragma unroll
    for (int m = 32; m; m >>= 1) {
        nv      += __shfl_xor(nv, m, 64);
        contrib += __shfl_xor(contrib, m, 64);
    }
    if (e == 0) out[2 * NTOK] = 64.0f * contrib / (nv * nv);
}

__global__ void finalize_kernel(const int* __restrict__ pk, const int* __restrict__ offs,
                                float* __restrict__ out)
{
    const int i = blockIdx.x * 256 + threadIdx.x;
    const int v = pk[i];
    const int e = v & 63;
    const int r = (v >> 6) + offs[(i >> 7) * NE + e];
    out[i] = (r < CAP) ? (float)e : -1.0f;
}

extern "C" void kernel_launch(void* const* d_in, const int* in_sizes, int n_in,
                              void* d_out, int out_size, void* d_ws, size_t ws_size,
                              hipStream_t stream)
{
    (void)in_sizes; (void)n_in; (void)out_size; (void)ws_size;
    const float* A     = (const float*)d_in[0];
    const float* W     = (const float*)d_in[1];
    const float* bias  = (const float*)d_in[2];
    const float* noise = (const float*)d_in[3];
    float* out = (float*)d_out;

    char* ws = (char*)d_ws;
    int*   bi_arr  = (int*)ws;                         // 512 KB
    int*   list    = (int*)(ws + 524288);              // 512 KB (gate->rescue)
    int*   pk      = (int*)(ws + 524288);              // aliased: rank(after rescue)->finalize
    int*   histg   = (int*)(ws + 1048576);             // 256 KB (offsets in-place)
    float* colpart = (float*)(ws + 1310720);           // 1 MB (4096 blocks x 64)
    int*   totals  = (int*)(ws + 2359296);             // 256 B
    float* colsums = (float*)(ws + 2359552);           // 256 B
    int*   cnt     = (int*)(ws + 2359808);             // 4 B
    uint4* Wp      = (uint4*)(ws + 2363392);           // 256 KB (2 bf16 planes, frag order)

    wprep_kernel<<<NCHUNK, 256, 0, stream>>>(W, Wp, cnt);
    gate_kernel<<<NBLK, 64, 0, stream>>>(A, Wp, bias, noise, out, bi_arr, list, cnt, colpart);
    rescue_kernel<<<256, 64, 0, stream>>>(A, W, bias, noise, list, cnt, bi_arr, out);
    rank_kernel<<<NTOK / 128, 64, 0, stream>>>(bi_arr, pk, histg);
    scan_kernel<<<NE, 256, 0, stream>>>(histg, colpart, totals, colsums);
    loss_kernel<<<1, 64, 0, stream>>>(totals, colsums, out);
    finalize_kernel<<<NTOK / 256, 256, 0, stream>>>(pk, histg, out);
}

// Round 12
// 268.842 us; speedup vs baseline: 1.4892x; 1.0708x over previous
//
#include <hip/hip_runtime.h>
#include <stdint.h>

#define NTOK   131072
#define DM     1024
#define NE     64
#define TB     32         // tokens per gate block (1 wave)
#define NBLK   4096       // NTOK / TB
#define BK     32         // K chunk (floats)
#define NCHUNK 32         // DM / BK
#define CAP    2458       // ceil(1.2 * 131072 / 64)
#define TAU    0.002f     // rescue threshold: >> ~4e-5 2-plane split error bound

typedef __attribute__((ext_vector_type(8))) short bf16x8;
typedef __attribute__((ext_vector_type(4))) float f32x4;

union Frag { bf16x8 v; uint32_t w[4]; uint4 q; unsigned short u[8]; };

// RNE fp32 -> bf16 bits (wprep only)
__device__ __forceinline__ unsigned short f2bf_rne(float x) {
    uint32_t u = __float_as_uint(x);
    u += 0x7FFFu + ((u >> 16) & 1u);
    return (unsigned short)(u >> 16);
}
__device__ __forceinline__ float bf2f(unsigned short h) {
    return __uint_as_float(((uint32_t)h) << 16);
}

// global -> LDS direct (16B/lane; gptr is the PER-LANE source address,
// LDS dest = wave-uniform base + lane*16)
__device__ __forceinline__ void gload_lds16(const float* g, float* l) {
    __builtin_amdgcn_global_load_lds(
        (const __attribute__((address_space(1))) void*)g,
        (__attribute__((address_space(3))) void*)l, 16, 0, 0);
}

// ---------------------------------------------------------------------------
// wprep: split W (1024x64 fp32) into 2 bf16 planes in MFMA B-frag order.
// Wp[(c*8 + t*2 + p)*64 + l]: col = t*16+(l&15), k = c*32+(l>>4)*8+j.
// Also zeroes the rescue counter.
// ---------------------------------------------------------------------------
__global__ __launch_bounds__(256)
void wprep_kernel(const float* __restrict__ W, uint4* __restrict__ Wp, int* __restrict__ cnt)
{
    if (blockIdx.x == 0 && threadIdx.x == 0) *cnt = 0;
    const int c = blockIdx.x;          // k-chunk 0..31
    const int t = threadIdx.x >> 6;    // n-tile 0..3
    const int l = threadIdx.x & 63;
    Frag p1, p2;
#pragma unroll
    for (int j = 0; j < 8; ++j) {
        const float wv = W[(size_t)(c * 32 + (l >> 4) * 8 + j) * NE + t * 16 + (l & 15)];
        const unsigned short h1 = f2bf_rne(wv);
        const unsigned short h2 = f2bf_rne(wv - bf2f(h1));
        p1.u[j] = h1; p2.u[j] = h2;
    }
    uint4* base = Wp + (size_t)(c * 8 + t * 2) * 64;
    base[0 * 64 + l] = p1.q;
    base[1 * 64 + l] = p2.q;
}

// 2-plane split of 8 fp32 via packed HW convert (rounding-mode agnostic:
// the residual subtraction is exact for any rounding of the first plane).
__device__ __forceinline__ void splitA(const float4& P0, const float4& P1,
                                       Frag& A1, Frag& A2)
{
    const float xs[8] = {P0.x, P0.y, P0.z, P0.w, P1.x, P1.y, P1.z, P1.w};
#pragma unroll
    for (int j = 0; j < 4; ++j) {
        uint32_t p1, p2;
        asm("v_cvt_pk_bf16_f32 %0, %1, %2" : "=v"(p1) : "v"(xs[2*j]), "v"(xs[2*j+1]));
        const float f0 = __uint_as_float(p1 << 16);
        const float f1 = __uint_as_float(p1 & 0xffff0000u);
        const float r0 = xs[2*j] - f0;
        const float r1 = xs[2*j+1] - f1;
        asm("v_cvt_pk_bf16_f32 %0, %1, %2" : "=v"(p2) : "v"(r0), "v"(r1));
        A1.w[j] = p1; A2.w[j] = p2;
    }
}

// ---------------------------------------------------------------------------
// gate_kernel (R12): 1 wave/block, 32 tokens, no barriers (R11 structure).
// R11 post-mortem: B took a needless global->LDS->reg round trip and shared
// the manual vmcnt with A. R12: B-frags load DIRECTLY to registers (plain
// per-lane uint4 loads, coalesced 1 KB, L2-resident Wp; compiler-managed
// waits let A-stage gloads stay in flight across the B-use wait). Manual
// vmcnt only covers the A gload_lds -> ds_read hazard (compiler can't see
// that dependency). LDS = A dbuf only (8 KB -> ~19 blocks/CU by LDS).
// FIFO: loop-top outstanding = A(c)=4; +B(c)=8 -> 12; +A(c+1)=4 -> 16;
// vmcnt(12) retires exactly A(c) (oldest) for any B/A interleave. Tail: (8).
// 3-term split MFMA: a.w ~= a1w1 + a1w2 + a2w1 (err ~2e-5 << TAU).
// ---------------------------------------------------------------------------
__global__ __launch_bounds__(64, 4)
void gate_kernel(const float* __restrict__ A, const uint4* __restrict__ Wp,
                 const float* __restrict__ bias, const float* __restrict__ noise,
                 float* __restrict__ out, int* __restrict__ bi_arr,
                 int* __restrict__ list, int* __restrict__ cnt,
                 float* __restrict__ colpart)
{
    __shared__ __align__(16) float aLds[2][TB][BK];  // 8 KB, swizzled slots

    const int lane = threadIdx.x;
    const int blk  = blockIdx.x;
    const int tokBase = blk * TB;
    const int g    = lane >> 4;
    const int e16  = lane & 15;

    f32x4 acc[2][4];
#pragma unroll
    for (int mt = 0; mt < 2; ++mt)
#pragma unroll
        for (int nt = 0; nt < 4; ++nt)
            acc[mt][nt] = (f32x4){0.f, 0.f, 0.f, 0.f};

    // A staging source: row r stores logical 16B-slot s at phys s^(r&7);
    // lane covers row q*8+(lane>>3), phys slot lane&7 (rule #21 both-sides).
    const int sl = (lane & 7) ^ ((lane >> 3) & 7);
    const float* aSrc = A + (size_t)(tokBase + (lane >> 3)) * DM + sl * 4;

#define STAGEA(c, b) {                                                        \
        _Pragma("unroll")                                                     \
        for (int q_ = 0; q_ < 4; ++q_)                                        \
            gload_lds16(aSrc + (size_t)q_ * 8 * DM + (c) * BK,                \
                        &aLds[b][q_ * 8][0]);                                 \
    }

#define CHUNK(c, cur) {                                                       \
        /* B(c) frags -> registers (compiler-tracked waits) */                \
        uint4 B_[8];                                                          \
        _Pragma("unroll")                                                     \
        for (int u_ = 0; u_ < 8; ++u_)                                        \
            B_[u_] = Wp[((size_t)(c) * 8 + u_) * 64 + lane];                  \
        if ((c) + 1 < NCHUNK) {                                               \
            STAGEA((c) + 1, (cur) ^ 1)                                        \
            asm volatile("s_waitcnt vmcnt(12)" ::: "memory"); /* A(c) landed */\
        } else {                                                              \
            asm volatile("s_waitcnt vmcnt(8)" ::: "memory");                  \
        }                                                                     \
        __builtin_amdgcn_sched_barrier(0);                                    \
        Frag a1_[2], a2_[2];                                                  \
        _Pragma("unroll")                                                     \
        for (int mt_ = 0; mt_ < 2; ++mt_) {                                   \
            const float* rp_ = &aLds[cur][mt_ * 16 + e16][0];                 \
            const float4 x0_ = *(const float4*)(rp_ + (((2*g)   ^ (e16 & 7)) << 2)); \
            const float4 x1_ = *(const float4*)(rp_ + (((2*g+1) ^ (e16 & 7)) << 2)); \
            splitA(x0_, x1_, a1_[mt_], a2_[mt_]);                             \
        }                                                                     \
        _Pragma("unroll")                                                     \
        for (int nt_ = 0; nt_ < 4; ++nt_) {                                   \
            Frag b1_, b2_;                                                    \
            b1_.q = B_[nt_ * 2];                                              \
            b2_.q = B_[nt_ * 2 + 1];                                          \
            _Pragma("unroll")                                                 \
            for (int mt_ = 0; mt_ < 2; ++mt_) {                               \
                f32x4 d_ = acc[mt_][nt_];                                     \
                d_ = __builtin_amdgcn_mfma_f32_16x16x32_bf16(a1_[mt_].v, b1_.v, d_, 0, 0, 0); \
                d_ = __builtin_amdgcn_mfma_f32_16x16x32_bf16(a1_[mt_].v, b2_.v, d_, 0, 0, 0); \
                d_ = __builtin_amdgcn_mfma_f32_16x16x32_bf16(a2_[mt_].v, b1_.v, d_, 0, 0, 0); \
                acc[mt_][nt_] = d_;                                           \
            }                                                                 \
        }                                                                     \
    }

    STAGEA(0, 0)
#pragma unroll 1
    for (int cc = 0; cc < NCHUNK; cc += 2) {
        CHUNK(cc,     0)
        CHUNK(cc + 1, 1)
    }
#undef CHUNK
#undef STAGEA

    // ---- epilogue: bias+noise, per-token argmax/softmax, rescue-list ----
    // C/D: token = mt*16 + g*4 + r (row), expert = nt*16 + e16 (col) [m89]
#pragma unroll
    for (int mt = 0; mt < 2; ++mt)
#pragma unroll
        for (int r = 0; r < 4; ++r) {
            const int T = tokBase + mt * 16 + g * 4 + r;
#pragma unroll
            for (int nt = 0; nt < 4; ++nt) {
                const float nz = noise[(size_t)T * NE + nt * 16 + e16];
                acc[mt][nt][r] += bias[nt * 16 + e16] + nz * 0.2f + 0.9f;
            }
        }

    float cw[4] = {0.f, 0.f, 0.f, 0.f};
#pragma unroll
    for (int mt = 0; mt < 2; ++mt)
#pragma unroll
        for (int r = 0; r < 4; ++r) {
            const int T = tokBase + mt * 16 + g * 4 + r;
            float raw[4];
#pragma unroll
            for (int nt = 0; nt < 4; ++nt) raw[nt] = acc[mt][nt][r];

            float v = raw[0]; int be = e16;
#pragma unroll
            for (int nt = 1; nt < 4; ++nt)
                if (raw[nt] > v) { v = raw[nt]; be = nt * 16 + e16; }
#pragma unroll
            for (int m = 1; m <= 8; m <<= 1) {
                const float vo = __shfl_xor(v, m, 64);
                const int   eo = __shfl_xor(be, m, 64);
                if (vo > v || (vo == v && eo < be)) { v = vo; be = eo; }
            }
            float m2 = -1e30f;                          // runner-up
#pragma unroll
            for (int nt = 0; nt < 4; ++nt)
                if (nt * 16 + e16 != be && raw[nt] > m2) m2 = raw[nt];
#pragma unroll
            for (int m = 1; m <= 8; m <<= 1)
                m2 = fmaxf(m2, __shfl_xor(m2, m, 64));

            float d = 0.f, pr[4];
#pragma unroll
            for (int nt = 0; nt < 4; ++nt) { pr[nt] = __expf(raw[nt] - v); d += pr[nt]; }
#pragma unroll
            for (int m = 1; m <= 8; m <<= 1) d += __shfl_xor(d, m, 64);
            const float inv = 1.0f / d;
#pragma unroll
            for (int nt = 0; nt < 4; ++nt) cw[nt] += pr[nt] * inv;

            if (e16 == mt * 4 + r) {                    // one writer per (g,mt,r)
                out[NTOK + T] = inv;
                bi_arr[T]     = be;
                if (v - m2 < TAU) {                     // borderline -> rescue
                    const int s = atomicAdd(cnt, 1);
                    list[s] = T;
                }
            }
        }

    // per-expert column sums over this wave's 32 tokens
#pragma unroll
    for (int nt = 0; nt < 4; ++nt) {
        cw[nt] += __shfl_xor(cw[nt], 16, 64);
        cw[nt] += __shfl_xor(cw[nt], 32, 64);
    }
    if (lane < 16) {
#pragma unroll
        for (int nt = 0; nt < 4; ++nt)
            colpart[blk * NE + nt * 16 + lane] = cw[nt];
    }
}

// ---------------------------------------------------------------------------
// rescue: recompute listed tokens with the bit-identical R5 sequential-fmaf
// chain (k ascending) so borderline argmax decisions match the fp32 path.
// ---------------------------------------------------------------------------
__device__ __forceinline__ void rescue_finish(int t, float sc, int lane,
                                              int* bi_arr, float* out)
{
    float v = sc; int be = lane;
#pragma unroll
    for (int m = 1; m <= 32; m <<= 1) {
        const float vo = __shfl_xor(v, m, 64);
        const int   eo = __shfl_xor(be, m, 64);
        if (vo > v || (vo == v && eo < be)) { v = vo; be = eo; }
    }
    float d = __expf(sc - v);
#pragma unroll
    for (int m = 1; m <= 32; m <<= 1) d += __shfl_xor(d, m, 64);
    if (lane == 0) { bi_arr[t] = be; out[NTOK + t] = 1.0f / d; }
}

__global__ __launch_bounds__(64)
void rescue_kernel(const float* __restrict__ A, const float* __restrict__ W,
                   const float* __restrict__ bias, const float* __restrict__ noise,
                   const int* __restrict__ list, const int* __restrict__ cnt,
                   int* __restrict__ bi_arr, float* __restrict__ out)
{
    const int lane = threadIdx.x;
    const int n = *cnt;
#pragma unroll 1
    for (int i0 = blockIdx.x * 4; i0 < n; i0 += 256 * 4) {
        const int t0 = list[i0];
        const int t1 = (i0 + 1 < n) ? list[i0 + 1] : t0;
        const int t2 = (i0 + 2 < n) ? list[i0 + 2] : t0;
        const int t3 = (i0 + 3 < n) ? list[i0 + 3] : t0;
        const float* r0 = A + (size_t)t0 * DM;
        const float* r1 = A + (size_t)t1 * DM;
        const float* r2 = A + (size_t)t2 * DM;
        const float* r3 = A + (size_t)t3 * DM;
        float a0 = 0.f, a1 = 0.f, a2 = 0.f, a3 = 0.f;
#pragma unroll 4
        for (int k = 0; k < DM; ++k) {
            const float wk = W[(size_t)k * NE + lane];
            a0 = fmaf(r0[k], wk, a0);
            a1 = fmaf(r1[k], wk, a1);
            a2 = fmaf(r2[k], wk, a2);
            a3 = fmaf(r3[k], wk, a3);
        }
        const float bl = bias[lane];
        rescue_finish(t0, a0 + bl + noise[(size_t)t0 * NE + lane] * 0.2f + 0.9f, lane, bi_arr, out);
        rescue_finish(t1, a1 + bl + noise[(size_t)t1 * NE + lane] * 0.2f + 0.9f, lane, bi_arr, out);
        rescue_finish(t2, a2 + bl + noise[(size_t)t2 * NE + lane] * 0.2f + 0.9f, lane, bi_arr, out);
        rescue_finish(t3, a3 + bl + noise[(size_t)t3 * NE + lane] * 0.2f + 0.9f, lane, bi_arr, out);
    }
}

// ---------------------------------------------------------------------------
// rank: stable within-128-token-block rank + histogram via ballots.
// ---------------------------------------------------------------------------
__global__ __launch_bounds__(64)
void rank_kernel(const int* __restrict__ bi_arr, int* __restrict__ pk,
                 int* __restrict__ histg)
{
    const int b    = blockIdx.x;
    const int lane = threadIdx.x;
    const uint64_t below = (1ull << lane) - 1ull;
    const int t0 = b * 128;
    const int b0 = bi_arr[t0 + lane];
    const int b1 = bi_arr[t0 + 64 + lane];
    int lr0 = 0, lr1 = 0, h0 = 0, h1 = 0, h0my = 0;
#pragma unroll 1
    for (int e = 0; e < NE; ++e) {
        const uint64_t m0 = __ballot(b0 == e);
        const uint64_t m1 = __ballot(b1 == e);
        if (b0 == e)   lr0 = (int)__popcll(m0 & below);
        if (b1 == e) { lr1 = (int)__popcll(m1 & below); h0my = (int)__popcll(m0); }
        if (lane == e) { h0 = (int)__popcll(m0); h1 = (int)__popcll(m1); }
    }
    pk[t0 + lane]      = b0 | (lr0 << 6);
    pk[t0 + 64 + lane] = b1 | ((lr1 + h0my) << 6);
    histg[b * NE + lane] = h0 + h1;
}

// ---------------------------------------------------------------------------
// scan: per-expert exclusive scan over 1024 rank-block histograms (in-place)
// + per-expert totals and softmax column sums (colpart: 4096 gate blocks).
// ---------------------------------------------------------------------------
__global__ __launch_bounds__(256)
void scan_kernel(int* __restrict__ hist, const float* __restrict__ colpart,
                 int* __restrict__ totals, float* __restrict__ colsums)
{
    __shared__ int   wtot[4];
    __shared__ float wcs[4];
    const int e = blockIdx.x, t = threadIdx.x, lane = t & 63, w = t >> 6;

    int h[4]; int s = 0; float csl = 0.f;
#pragma unroll
    for (int i = 0; i < 4; ++i) {
        h[i] = hist[(t * 4 + i) * NE + e];
        s   += h[i];
    }
#pragma unroll
    for (int i = 0; i < 16; ++i)
        csl += colpart[(t * 16 + i) * NE + e];

    int inc = s;
#pragma unroll
    for (int d = 1; d < 64; d <<= 1) {
        const int v = __shfl_up(inc, d, 64);
        if (lane >= d) inc += v;
    }
    float wsum = csl;
#pragma unroll
    for (int m = 32; m; m >>= 1) wsum += __shfl_xor(wsum, m, 64);
    if (lane == 63) wtot[w] = inc;
    if (lane == 0)  wcs[w]  = wsum;
    __syncthreads();

    int base = 0;
#pragma unroll
    for (int ww = 0; ww < 4; ++ww) base += (ww < w) ? wtot[ww] : 0;
    int run = base + inc - s;
#pragma unroll
    for (int i = 0; i < 4; ++i) { hist[(t * 4 + i) * NE + e] = run; run += h[i]; }

    if (t == 0) {
        totals[e]  = wtot[0] + wtot[1] + wtot[2] + wtot[3];
        colsums[e] = wcs[0] + wcs[1] + wcs[2] + wcs[3];
    }
}

__global__ void loss_kernel(const int* __restrict__ totals,
                            const float* __restrict__ colsums,
                            float* __restrict__ out)
{
    const int e   = threadIdx.x;
    const int tot = totals[e];
    const float cnt = (float)((tot < CAP) ? tot : CAP);
    float nv = cnt, contrib = cnt * colsums[e];
#pragma unroll
    for (int m = 32; m; m >>= 1) {
        nv      += __shfl_xor(nv, m, 64);
        contrib += __shfl_xor(contrib, m, 64);
    }
    if (e == 0) out[2 * NTOK] = 64.0f * contrib / (nv * nv);
}

__global__ void finalize_kernel(const int* __restrict__ pk, const int* __restrict__ offs,
                                float* __restrict__ out)
{
    const int i = blockIdx.x * 256 + threadIdx.x;
    const int v = pk[i];
    const int e = v & 63;
    const int r = (v >> 6) + offs[(i >> 7) * NE + e];
    out[i] = (r < CAP) ? (float)e : -1.0f;
}

extern "C" void kernel_launch(void* const* d_in, const int* in_sizes, int n_in,
                              void* d_out, int out_size, void* d_ws, size_t ws_size,
                              hipStream_t stream)
{
    (void)in_sizes; (void)n_in; (void)out_size; (void)ws_size;
    const float* A     = (const float*)d_in[0];
    const float* W     = (const float*)d_in[1];
    const float* bias  = (const float*)d_in[2];
    const float* noise = (const float*)d_in[3];
    float* out = (float*)d_out;

    char* ws = (char*)d_ws;
    int*   bi_arr  = (int*)ws;                         // 512 KB
    int*   list    = (int*)(ws + 524288);              // 512 KB (gate->rescue)
    int*   pk      = (int*)(ws + 524288);              // aliased: rank(after rescue)->finalize
    int*   histg   = (int*)(ws + 1048576);             // 256 KB (offsets in-place)
    float* colpart = (float*)(ws + 1310720);           // 1 MB (4096 blocks x 64)
    int*   totals  = (int*)(ws + 2359296);             // 256 B
    float* colsums = (float*)(ws + 2359552);           // 256 B
    int*   cnt     = (int*)(ws + 2359808);             // 4 B
    uint4* Wp      = (uint4*)(ws + 2363392);           // 256 KB (2 bf16 planes, frag order)

    wprep_kernel<<<NCHUNK, 256, 0, stream>>>(W, Wp, cnt);
    gate_kernel<<<NBLK, 64, 0, stream>>>(A, Wp, bias, noise, out, bi_arr, list, cnt, colpart);
    rescue_kernel<<<256, 64, 0, stream>>>(A, W, bias, noise, list, cnt, bi_arr, out);
    rank_kernel<<<NTOK / 128, 64, 0, stream>>>(bi_arr, pk, histg);
    scan_kernel<<<NE, 256, 0, stream>>>(histg, colpart, totals, colsums);
    loss_kernel<<<1, 64, 0, stream>>>(totals, colsums, out);
    finalize_kernel<<<NTOK / 256, 256, 0, stream>>>(pk, histg, out);
}